// Round 1
// baseline (3723.359 us; speedup 1.0000x reference)
//
#include <hip/hip_runtime.h>

constexpr int BN = 2;       // batch
constexpr int TN = 1024;    // seq len
constexpr int DM = 1024;    // d_model
constexpr int DI = 2048;    // d_inner
constexpr int DS = 16;      // d_state
constexpr int RK = 64;      // dt_rank
constexpr int XD = 96;      // dt_rank + 2*d_state
constexpr int MROWS = BN * TN; // 2048

// C[m,n] = sum_k A[m*lda+k] * Bw[n*ldb+k]   (+ optional epilogue)
// EPI 0: none; EPI 1: softplus(acc + bias[n])
template<int EPI>
__global__ __launch_bounds__(256) void gemm_bt(const float* __restrict__ A,
    const float* __restrict__ Bw, float* __restrict__ C,
    int M, int N, int K, int lda, int ldb, int ldc,
    const float* __restrict__ bias) {
  __shared__ float As[16][65];
  __shared__ float Bs[16][65];
  int tid = threadIdx.x;
  int tx = tid & 15, ty = tid >> 4;
  int row0 = blockIdx.y * 64;
  int col0 = blockIdx.x * 64;
  float acc[4][4] = {};
  for (int k0 = 0; k0 < K; k0 += 16) {
#pragma unroll
    for (int i = tid; i < 1024; i += 256) {
      int r = i >> 4, kk = i & 15;
      int gm = row0 + r, gk = k0 + kk;
      As[kk][r] = (gm < M && gk < K) ? A[(long)gm * lda + gk] : 0.f;
      int gn = col0 + r;
      Bs[kk][r] = (gn < N && gk < K) ? Bw[(long)gn * ldb + gk] : 0.f;
    }
    __syncthreads();
#pragma unroll
    for (int kk = 0; kk < 16; ++kk) {
      float a[4], b[4];
#pragma unroll
      for (int j = 0; j < 4; ++j) { a[j] = As[kk][ty * 4 + j]; b[j] = Bs[kk][tx * 4 + j]; }
#pragma unroll
      for (int i = 0; i < 4; ++i)
#pragma unroll
        for (int j = 0; j < 4; ++j)
          acc[i][j] = fmaf(a[i], b[j], acc[i][j]);
    }
    __syncthreads();
  }
#pragma unroll
  for (int i = 0; i < 4; ++i) {
    int gm = row0 + ty * 4 + i;
    if (gm >= M) continue;
#pragma unroll
    for (int j = 0; j < 4; ++j) {
      int gn = col0 + tx * 4 + j;
      if (gn >= N) continue;
      float v = acc[i][j];
      if (EPI == 1) {
        v += bias[gn];
        v = (v > 20.f) ? v : log1pf(expf(v));
      }
      C[(long)gm * ldc + gn] = v;
    }
  }
}

// u[b,t,d] = silu( sum_k xc[b, t-3+k, d]*cw[d,k] + cb[d] )
// xc = xz[:, 0:DI] of the [MROWS, 2*DI] xz buffer
__global__ __launch_bounds__(256) void conv_silu_kernel(const float* __restrict__ xz,
    const float* __restrict__ cw, const float* __restrict__ cb,
    float* __restrict__ u) {
  int idx = blockIdx.x * 256 + threadIdx.x;     // over MROWS*DI
  int d = idx & (DI - 1);
  int bt = idx >> 11;                            // DI = 2048 = 2^11
  int t = bt & (TN - 1);
  long rowb = (long)(bt - t);                    // b*T
  float acc = cb[d];
#pragma unroll
  for (int k = 0; k < 4; ++k) {
    int ts = t - 3 + k;
    if (ts >= 0) acc = fmaf(xz[(rowb + ts) * (2 * DI) + d], cw[d * 4 + k], acc);
  }
  u[idx] = acc / (1.f + expf(-acc));
}

// Selective scan. 16 lanes per (b,d) channel: lane n owns state n.
// Fuses  y = (scan + u*Dskip) * silu(z).  y may alias u_in.
__global__ __launch_bounds__(256) void scan_kernel(const float* __restrict__ dt,
    const float* __restrict__ u_in, const float* __restrict__ xdbl,
    const float* __restrict__ xz, const float* __restrict__ A_log,
    const float* __restrict__ Dskip, float* __restrict__ y) {
  int tid = threadIdx.x;
  int n = tid & 15;
  int dl = tid >> 4;                      // 16 d-channels per block
  int blocksPerB = DI / 16;               // 128
  int b = blockIdx.x / blocksPerB;
  int dblk = blockIdx.x % blocksPerB;
  int d = dblk * 16 + dl;
  float Aval = -expf(A_log[d * DS + n]);
  float Dval = Dskip[d];
  float h = 0.f;
  const long rowBase = (long)b * TN;
  for (int t = 0; t < TN; ++t) {
    long row = rowBase + t;
    float dtv = dt[row * DI + d];
    float uv  = u_in[row * DI + d];
    float Bv  = xdbl[row * XD + RK + n];
    float Cv  = xdbl[row * XD + RK + DS + n];
    float dA = expf(dtv * Aval);
    h = fmaf(dA, h, dtv * uv * Bv);
    float py = h * Cv;
    py += __shfl_xor(py, 1);
    py += __shfl_xor(py, 2);
    py += __shfl_xor(py, 4);
    py += __shfl_xor(py, 8);
    if (n == 0) {
      float zv = xz[row * (2 * DI) + DI + d];
      float sz = zv / (1.f + expf(-zv));
      y[row * DI + d] = (py + uv * Dval) * sz;
    }
  }
}

// out[row,:] = LayerNorm(h[row,:]) * w + b + resid[row,:]
__global__ __launch_bounds__(256) void ln_res_kernel(const float* __restrict__ h,
    const float* __restrict__ resid, const float* __restrict__ w,
    const float* __restrict__ bb, float* __restrict__ out) {
  int row = blockIdx.x;
  int tid = threadIdx.x;
  const float4* hr = (const float4*)(h + (long)row * DM);
  float4 v = hr[tid];
  __shared__ float sm[256];
  float s = v.x + v.y + v.z + v.w;
  sm[tid] = s; __syncthreads();
  for (int st = 128; st > 0; st >>= 1) { if (tid < st) sm[tid] += sm[tid + st]; __syncthreads(); }
  float mean = sm[0] * (1.f / DM);
  __syncthreads();
  float4 c;
  c.x = v.x - mean; c.y = v.y - mean; c.z = v.z - mean; c.w = v.w - mean;
  float s2 = c.x * c.x + c.y * c.y + c.z * c.z + c.w * c.w;
  sm[tid] = s2; __syncthreads();
  for (int st = 128; st > 0; st >>= 1) { if (tid < st) sm[tid] += sm[tid + st]; __syncthreads(); }
  float inv = rsqrtf(sm[0] * (1.f / DM) + 1e-5f);
  const float4 rv = ((const float4*)(resid + (long)row * DM))[tid];
  const float4 wv = ((const float4*)w)[tid];
  const float4 bv = ((const float4*)bb)[tid];
  float4 o;
  o.x = c.x * inv * wv.x + bv.x + rv.x;
  o.y = c.y * inv * wv.y + bv.y + rv.y;
  o.z = c.z * inv * wv.z + bv.z + rv.z;
  o.w = c.w * inv * wv.w + bv.w + rv.w;
  ((float4*)(out + (long)row * DM))[tid] = o;
}

extern "C" void kernel_launch(void* const* d_in, const int* in_sizes, int n_in,
                              void* d_out, int out_size, void* d_ws, size_t ws_size,
                              hipStream_t stream) {
  const float* x     = (const float*)d_in[0];
  const float* inw   = (const float*)d_in[1];
  const float* convw = (const float*)d_in[2];
  const float* convb = (const float*)d_in[3];
  const float* xpw   = (const float*)d_in[4];
  const float* dtw   = (const float*)d_in[5];
  const float* dtbi  = (const float*)d_in[6];
  const float* alog  = (const float*)d_in[7];
  const float* dsk   = (const float*)d_in[8];
  const float* outw  = (const float*)d_in[9];
  const float* lnw   = (const float*)d_in[10];
  const float* lnb   = (const float*)d_in[11];
  float* outp = (float*)d_out;

  float* ws = (float*)d_ws;
  size_t o = 0;
  float* xzb  = ws + o; o += (size_t)MROWS * 2 * DI;  // 8M floats
  float* ub   = ws + o; o += (size_t)MROWS * DI;      // 4M (also y, in-place)
  float* xdb  = ws + o; o += (size_t)MROWS * XD;
  float* dtb2 = ws + o; o += (size_t)MROWS * DI;
  float* hb   = ws + o; o += (size_t)MROWS * DM;
  float* xcur = ws + o; o += (size_t)MROWS * DM;

  const float* lin = x;
  for (int l = 0; l < 2; ++l) {
    dim3 g1((2 * DI) / 64, MROWS / 64);
    gemm_bt<0><<<g1, 256, 0, stream>>>(lin, inw + (size_t)l * 2 * DI * DM, xzb,
        MROWS, 2 * DI, DM, DM, DM, 2 * DI, nullptr);

    conv_silu_kernel<<<(MROWS * DI) / 256, 256, 0, stream>>>(
        xzb, convw + (size_t)l * DI * 4, convb + (size_t)l * DI, ub);

    dim3 g2((XD + 63) / 64, MROWS / 64);
    gemm_bt<0><<<g2, 256, 0, stream>>>(ub, xpw + (size_t)l * XD * DI, xdb,
        MROWS, XD, DI, DI, DI, XD, nullptr);

    dim3 g3(DI / 64, MROWS / 64);
    gemm_bt<1><<<g3, 256, 0, stream>>>(xdb, dtw + (size_t)l * DI * RK, dtb2,
        MROWS, DI, RK, XD, RK, DI, dtbi + (size_t)l * DI);

    scan_kernel<<<(BN * DI) / 16, 256, 0, stream>>>(dtb2, ub, xdb, xzb,
        alog + (size_t)l * DI * DS, dsk + (size_t)l * DI, ub);

    dim3 g4(DM / 64, MROWS / 64);
    gemm_bt<0><<<g4, 256, 0, stream>>>(ub, outw + (size_t)l * DM * DI, hb,
        MROWS, DM, DI, DI, DI, DM, nullptr);

    float* lout = (l == 0) ? xcur : outp;
    ln_res_kernel<<<MROWS, 256, 0, stream>>>(hb, lin,
        lnw + (size_t)l * DM, lnb + (size_t)l * DM, lout);
    lin = xcur;
  }
}

// Round 2
// 774.240 us; speedup vs baseline: 4.8091x; 4.8091x over previous
//
#include <hip/hip_runtime.h>

constexpr int BN = 2;       // batch
constexpr int TN = 1024;    // seq len
constexpr int DM = 1024;    // d_model
constexpr int DI = 2048;    // d_inner
constexpr int DS = 16;      // d_state
constexpr int RK = 64;      // dt_rank
constexpr int XD = 96;      // dt_rank + 2*d_state
constexpr int MROWS = BN * TN; // 2048
constexpr int NC = 16;      // scan chunks
constexpr int CL = 64;      // chunk length (NC*CL == TN)

using f32x4  = __attribute__((ext_vector_type(4))) float;
using bf16x8 = __attribute__((ext_vector_type(8))) short;

__device__ inline short f2b(float f) {
  union { float f; unsigned u; } v; v.f = f;
  unsigned r = (v.u + 0x7FFFu + ((v.u >> 16) & 1u)) >> 16;
  return (short)r;
}
__device__ inline float b2f(short s) {
  union { unsigned u; float f; } v; v.u = ((unsigned)(unsigned short)s) << 16;
  return v.f;
}

__device__ inline void gl_lds16(const void* g, void* l) {
  __builtin_amdgcn_global_load_lds((const __attribute__((address_space(1))) void*)g,
                                   (__attribute__((address_space(3))) void*)l, 16, 0, 0);
}

// fp32 -> bf16 convert, 4 elems/thread
__global__ __launch_bounds__(256) void f2bf_k(const float* __restrict__ in,
    short* __restrict__ out, int n4) {
  int i = blockIdx.x * 256 + threadIdx.x;
  if (i >= n4) return;
  float4 v = ((const float4*)in)[i];
  short4 s; s.x = f2b(v.x); s.y = f2b(v.y); s.z = f2b(v.z); s.w = f2b(v.w);
  ((short4*)out)[i] = s;
}

// ---------------- bf16 MFMA GEMM: C = A[M,K] * Bw[N,K]^T ----------------
// tile 128x128, BK=32, 4 waves (2x2), each wave 64x64 = 4x4 frags of 16x16x32
template<int OUT_BF16>
__global__ __launch_bounds__(256) void gemm_mfma(const short* __restrict__ A,
    const short* __restrict__ Bw, float* __restrict__ Cf, short* __restrict__ Cb,
    int M, int N, int K, int ldc) {
  __shared__ alignas(16) short As[128 * 32];
  __shared__ alignas(16) short Bs[128 * 32];
  const int tid = threadIdx.x;
  const int wid = tid >> 6, lane = tid & 63;
  const int row0 = blockIdx.y * 128, col0 = blockIdx.x * 128;
  const int wr = (wid >> 1) * 64, wc = (wid & 1) * 64;
  const int srow = tid >> 2;          // staging row within 64-row round
  const int scol = (tid & 3) * 8;     // staging col (8 bf16 = 16B)
  f32x4 acc[4][4] = {};

  for (int k0 = 0; k0 < K; k0 += 32) {
#pragma unroll
    for (int r = 0; r < 2; ++r) {
      gl_lds16(A  + (long)(row0 + r * 64 + srow) * K + k0 + scol,
               (short*)((char*)As + r * 4096 + wid * 1024));
      gl_lds16(Bw + (long)(col0 + r * 64 + srow) * K + k0 + scol,
               (short*)((char*)Bs + r * 4096 + wid * 1024));
    }
    __syncthreads();
    bf16x8 af[4], bv[4];
#pragma unroll
    for (int i = 0; i < 4; ++i)
      af[i] = *(const bf16x8*)(As + (wr + i * 16 + (lane & 15)) * 32 + (lane >> 4) * 8);
#pragma unroll
    for (int j = 0; j < 4; ++j)
      bv[j] = *(const bf16x8*)(Bs + (wc + j * 16 + (lane & 15)) * 32 + (lane >> 4) * 8);
#pragma unroll
    for (int i = 0; i < 4; ++i)
#pragma unroll
      for (int j = 0; j < 4; ++j)
        acc[i][j] = __builtin_amdgcn_mfma_f32_16x16x32_bf16(af[i], bv[j], acc[i][j], 0, 0, 0);
    __syncthreads();
  }
#pragma unroll
  for (int i = 0; i < 4; ++i) {
#pragma unroll
    for (int j = 0; j < 4; ++j) {
      int gcol = col0 + wc + j * 16 + (lane & 15);
#pragma unroll
      for (int r = 0; r < 4; ++r) {
        int grow = row0 + wr + i * 16 + (lane >> 4) * 4 + r;
        if (OUT_BF16) Cb[(long)grow * ldc + gcol] = f2b(acc[i][j][r]);
        else          Cf[(long)grow * ldc + gcol] = acc[i][j][r];
      }
    }
  }
}

// ---------------- fp32 vector GEMM (small matrices), optional split-K ----
// C[z][m][n] = sum_{k in split z} A[m,k]*Bw[n,k]  (+ EPI=1: softplus(acc+bias[n]))
template<int EPI>
__global__ __launch_bounds__(256) void gemm_bt(const float* __restrict__ A,
    const float* __restrict__ Bw, float* __restrict__ C,
    int M, int N, int K, int lda, int ldb, int ldc,
    const float* __restrict__ bias, int ksplit) {
  __shared__ float As[16][65];
  __shared__ float Bs[16][65];
  int tid = threadIdx.x;
  int tx = tid & 15, ty = tid >> 4;
  int row0 = blockIdx.y * 64;
  int col0 = blockIdx.x * 64;
  int kbeg = blockIdx.z * ksplit;
  int kend = kbeg + ksplit; if (kend > K) kend = K;
  float acc[4][4] = {};
  for (int k0 = kbeg; k0 < kend; k0 += 16) {
#pragma unroll
    for (int i = tid; i < 1024; i += 256) {
      int r = i >> 4, kk = i & 15;
      int gm = row0 + r, gk = k0 + kk;
      As[kk][r] = (gm < M && gk < K) ? A[(long)gm * lda + gk] : 0.f;
      int gn = col0 + r;
      Bs[kk][r] = (gn < N && gk < K) ? Bw[(long)gn * ldb + gk] : 0.f;
    }
    __syncthreads();
#pragma unroll
    for (int kk = 0; kk < 16; ++kk) {
      float a[4], b[4];
#pragma unroll
      for (int j = 0; j < 4; ++j) { a[j] = As[kk][ty * 4 + j]; b[j] = Bs[kk][tx * 4 + j]; }
#pragma unroll
      for (int i = 0; i < 4; ++i)
#pragma unroll
        for (int j = 0; j < 4; ++j)
          acc[i][j] = fmaf(a[i], b[j], acc[i][j]);
    }
    __syncthreads();
  }
#pragma unroll
  for (int i = 0; i < 4; ++i) {
    int gm = row0 + ty * 4 + i;
    if (gm >= M) continue;
#pragma unroll
    for (int j = 0; j < 4; ++j) {
      int gn = col0 + tx * 4 + j;
      if (gn >= N) continue;
      float v = acc[i][j];
      if (EPI == 1) {
        v += bias[gn];
        v = (v > 20.f) ? v : log1pf(expf(v));
      }
      C[((long)blockIdx.z * M + gm) * ldc + gn] = v;
    }
  }
}

// sum 4 split-K partials of x_proj
__global__ __launch_bounds__(256) void reduce_xp(const float* __restrict__ part,
    float* __restrict__ out) {
  int i = blockIdx.x * 256 + threadIdx.x;   // over MROWS*XD
  const int n = MROWS * XD;
  out[i] = part[i] + part[n + i] + part[2 * n + i] + part[3 * n + i];
}

// u = silu(causal depthwise conv(xc) + cb), xc = xz[:, 0:DI] (bf16 in)
__global__ __launch_bounds__(256) void conv_silu(const short* __restrict__ xz,
    const float* __restrict__ cw, const float* __restrict__ cb,
    float* __restrict__ u) {
  int idx = blockIdx.x * 256 + threadIdx.x;  // MROWS*DI
  int d = idx & (DI - 1);
  int bt = idx >> 11;
  int t = bt & (TN - 1);
  long rowb = (long)(bt - t);
  float acc = cb[d];
#pragma unroll
  for (int k = 0; k < 4; ++k) {
    int ts = t - 3 + k;
    if (ts >= 0) acc = fmaf(b2f(xz[(rowb + ts) * (2 * DI) + d]), cw[d * 4 + k], acc);
  }
  u[idx] = acc / (1.f + expf(-acc));
}

// ---------------- chunked selective scan ----------------
// phase 1: per-chunk local scan (h0=0) + decay product
__global__ __launch_bounds__(256) void scan_p1(const float* __restrict__ dt,
    const float* __restrict__ u, const float* __restrict__ xdbl,
    const float* __restrict__ A_log, float* __restrict__ hloc,
    float* __restrict__ prodb) {
  int tid = threadIdx.x; int n = tid & 15, dl = tid >> 4;
  int bid = blockIdx.x;                 // ((c*BN + b)*128 + dblk)
  int dblk = bid & 127, cb_ = bid >> 7, b = cb_ & 1, c = cb_ >> 1;
  int d = dblk * 16 + dl;
  float Av = -expf(A_log[d * DS + n]);
  float h = 0.f, sdt = 0.f;
  long row = (long)b * TN + c * CL;
  for (int t = 0; t < CL; ++t) {
    long rw = row + t;
    float dtv = dt[rw * DI + d];
    float uv  = u[rw * DI + d];
    float Bv  = xdbl[rw * XD + RK + n];
    sdt += dtv;
    h = fmaf(expf(dtv * Av), h, dtv * uv * Bv);
  }
  long o = (((long)c * BN + b) * DI + d) * DS + n;
  hloc[o] = h;
  prodb[o] = expf(sdt * Av);
}

// phase 2: sequential combine over chunks (per state)
__global__ __launch_bounds__(256) void scan_p2(const float* __restrict__ hloc,
    const float* __restrict__ prodb, float* __restrict__ h0) {
  long idx = blockIdx.x * 256 + threadIdx.x;  // BN*DI*DS = 65536
  float carry = 0.f;
#pragma unroll
  for (int c = 0; c < NC; ++c) {
    long o = (long)c * (BN * DI * DS) + idx;
    h0[o] = carry;
    carry = fmaf(prodb[o], carry, hloc[o]);
  }
}

// phase 3: replay chunk from carried state, emit y (bf16) = (h.C + u*D)*silu(z)
__global__ __launch_bounds__(256) void scan_p3(const float* __restrict__ dt,
    const float* __restrict__ u, const float* __restrict__ xdbl,
    const short* __restrict__ xz, const float* __restrict__ A_log,
    const float* __restrict__ Dskip, const float* __restrict__ h0,
    short* __restrict__ ybf) {
  int tid = threadIdx.x; int n = tid & 15, dl = tid >> 4;
  int bid = blockIdx.x;
  int dblk = bid & 127, cb_ = bid >> 7, b = cb_ & 1, c = cb_ >> 1;
  int d = dblk * 16 + dl;
  float Av = -expf(A_log[d * DS + n]);
  float Dval = Dskip[d];
  long o = (((long)c * BN + b) * DI + d) * DS + n;
  float h = h0[o];
  long row = (long)b * TN + c * CL;
  for (int t = 0; t < CL; ++t) {
    long rw = row + t;
    float dtv = dt[rw * DI + d];
    float uv  = u[rw * DI + d];
    float Bv  = xdbl[rw * XD + RK + n];
    float Cv  = xdbl[rw * XD + RK + DS + n];
    h = fmaf(expf(dtv * Av), h, dtv * uv * Bv);
    float py = h * Cv;
    py += __shfl_xor(py, 1);
    py += __shfl_xor(py, 2);
    py += __shfl_xor(py, 4);
    py += __shfl_xor(py, 8);
    if (n == 0) {
      float zv = b2f(xz[rw * (2 * DI) + DI + d]);
      float sz = zv / (1.f + expf(-zv));
      ybf[rw * DI + d] = f2b((py + uv * Dval) * sz);
    }
  }
}

// out = LN(h)*w + b + resid ; optional bf16 copy of out
__global__ __launch_bounds__(256) void ln_res(const float* __restrict__ h,
    const float* __restrict__ resid, const float* __restrict__ w,
    const float* __restrict__ bb, float* __restrict__ out, short* __restrict__ ob) {
  int row = blockIdx.x;
  int tid = threadIdx.x;
  const float4* hr = (const float4*)(h + (long)row * DM);
  float4 v = hr[tid];
  __shared__ float sm[256];
  float s = v.x + v.y + v.z + v.w;
  sm[tid] = s; __syncthreads();
  for (int st = 128; st > 0; st >>= 1) { if (tid < st) sm[tid] += sm[tid + st]; __syncthreads(); }
  float mean = sm[0] * (1.f / DM);
  __syncthreads();
  float4 c;
  c.x = v.x - mean; c.y = v.y - mean; c.z = v.z - mean; c.w = v.w - mean;
  float s2 = c.x * c.x + c.y * c.y + c.z * c.z + c.w * c.w;
  sm[tid] = s2; __syncthreads();
  for (int st = 128; st > 0; st >>= 1) { if (tid < st) sm[tid] += sm[tid + st]; __syncthreads(); }
  float inv = rsqrtf(sm[0] * (1.f / DM) + 1e-5f);
  const float4 rv = ((const float4*)(resid + (long)row * DM))[tid];
  const float4 wv = ((const float4*)w)[tid];
  const float4 bv = ((const float4*)bb)[tid];
  float4 ov;
  ov.x = c.x * inv * wv.x + bv.x + rv.x;
  ov.y = c.y * inv * wv.y + bv.y + rv.y;
  ov.z = c.z * inv * wv.z + bv.z + rv.z;
  ov.w = c.w * inv * wv.w + bv.w + rv.w;
  ((float4*)(out + (long)row * DM))[tid] = ov;
  if (ob) {
    short4 sv; sv.x = f2b(ov.x); sv.y = f2b(ov.y); sv.z = f2b(ov.z); sv.w = f2b(ov.w);
    *(short4*)(ob + (long)row * DM + tid * 4) = sv;
  }
}

extern "C" void kernel_launch(void* const* d_in, const int* in_sizes, int n_in,
                              void* d_out, int out_size, void* d_ws, size_t ws_size,
                              hipStream_t stream) {
  const float* x     = (const float*)d_in[0];
  const float* inw   = (const float*)d_in[1];
  const float* convw = (const float*)d_in[2];
  const float* convb = (const float*)d_in[3];
  const float* xpw   = (const float*)d_in[4];
  const float* dtw   = (const float*)d_in[5];
  const float* dtbi  = (const float*)d_in[6];
  const float* alog  = (const float*)d_in[7];
  const float* dsk   = (const float*)d_in[8];
  const float* outw  = (const float*)d_in[9];
  const float* lnw   = (const float*)d_in[10];
  const float* lnb   = (const float*)d_in[11];
  float* outp = (float*)d_out;

  char* w = (char*)d_ws; size_t off = 0;
  auto alloc = [&](size_t bytes) { void* p = w + off; off += (bytes + 255) & ~255ULL; return p; };
  short* inw_bf  = (short*)alloc((size_t)2 * DI * DM * 2);   // per-layer bf16 weights
  short* outw_bf = (short*)alloc((size_t)DM * DI * 2);
  short* abuf    = (short*)alloc((size_t)MROWS * DI * 2);    // xbf (first MROWS*DM) / ybf
  short* xzbf    = (short*)alloc((size_t)MROWS * 2 * DI * 2);
  float* ub      = (float*)alloc((size_t)MROWS * DI * 4);
  float* xpart   = (float*)alloc((size_t)4 * MROWS * XD * 4);
  float* xdb     = (float*)alloc((size_t)MROWS * XD * 4);
  float* dtb     = (float*)alloc((size_t)MROWS * DI * 4);
  float* hloc    = (float*)alloc((size_t)NC * BN * DI * DS * 4);
  float* prodb   = (float*)alloc((size_t)NC * BN * DI * DS * 4);
  float* h0      = (float*)alloc((size_t)NC * BN * DI * DS * 4);
  float* hb      = (float*)alloc((size_t)MROWS * DM * 4);
  float* xcur    = (float*)alloc((size_t)MROWS * DM * 4);

  // input x -> bf16
  f2bf_k<<<(MROWS * DM / 4 + 255) / 256, 256, 0, stream>>>(x, abuf, MROWS * DM / 4);

  const float* lin = x;
  for (int l = 0; l < 2; ++l) {
    f2bf_k<<<(2 * DI * DM / 4 + 255) / 256, 256, 0, stream>>>(
        inw + (size_t)l * 2 * DI * DM, inw_bf, 2 * DI * DM / 4);
    f2bf_k<<<(DM * DI / 4 + 255) / 256, 256, 0, stream>>>(
        outw + (size_t)l * DM * DI, outw_bf, DM * DI / 4);

    // in_proj: [2048,1024] x [4096,1024]^T -> bf16 xz
    gemm_mfma<1><<<dim3((2 * DI) / 128, MROWS / 128), 256, 0, stream>>>(
        abuf, inw_bf, nullptr, xzbf, MROWS, 2 * DI, DM, 2 * DI);

    conv_silu<<<(MROWS * DI) / 256, 256, 0, stream>>>(
        xzbf, convw + (size_t)l * DI * 4, convb + (size_t)l * DI, ub);

    // x_proj: split-K=4 fp32
    gemm_bt<0><<<dim3(2, MROWS / 64, 4), 256, 0, stream>>>(ub,
        xpw + (size_t)l * XD * DI, xpart, MROWS, XD, DI, DI, DI, XD, nullptr, DI / 4);
    reduce_xp<<<(MROWS * XD) / 256, 256, 0, stream>>>(xpart, xdb);

    // dt_proj + softplus
    gemm_bt<1><<<dim3(DI / 64, MROWS / 64, 1), 256, 0, stream>>>(xdb,
        dtw + (size_t)l * DI * RK, dtb, MROWS, DI, RK, XD, RK, DI,
        dtbi + (size_t)l * DI, RK);

    // chunked scan
    scan_p1<<<NC * BN * (DI / 16), 256, 0, stream>>>(dtb, ub, xdb,
        alog + (size_t)l * DI * DS, hloc, prodb);
    scan_p2<<<(BN * DI * DS) / 256, 256, 0, stream>>>(hloc, prodb, h0);
    scan_p3<<<NC * BN * (DI / 16), 256, 0, stream>>>(dtb, ub, xdb, xzbf,
        alog + (size_t)l * DI * DS, dsk + (size_t)l * DI, h0, abuf);

    // out_proj: [2048,2048] x [1024,2048]^T -> fp32 hb
    gemm_mfma<0><<<dim3(DM / 128, MROWS / 128), 256, 0, stream>>>(
        abuf, outw_bf, hb, nullptr, MROWS, DM, DI, DM);

    float* lo = (l == 0) ? xcur : outp;
    short* lob = (l == 0) ? abuf : nullptr;
    ln_res<<<MROWS, 256, 0, stream>>>(hb, lin,
        lnw + (size_t)l * DM, lnb + (size_t)l * DM, lo, lob);
    lin = xcur;
  }
}

// Round 3
// 616.496 us; speedup vs baseline: 6.0396x; 1.2559x over previous
//
#include <hip/hip_runtime.h>

constexpr int BN = 2;       // batch
constexpr int TN = 1024;    // seq len
constexpr int DM = 1024;    // d_model
constexpr int DI = 2048;    // d_inner
constexpr int DS = 16;      // d_state
constexpr int RK = 64;      // dt_rank
constexpr int XD = 96;      // dt_rank + 2*d_state
constexpr int MROWS = BN * TN; // 2048
constexpr int NC = 16;      // scan chunks
constexpr int CL = 64;      // chunk length (NC*CL == TN)

using f32x4  = __attribute__((ext_vector_type(4))) float;
using bf16x8 = __attribute__((ext_vector_type(8))) short;

__device__ inline short f2b(float f) {
  union { float f; unsigned u; } v; v.f = f;
  unsigned r = (v.u + 0x7FFFu + ((v.u >> 16) & 1u)) >> 16;
  return (short)r;
}
__device__ inline float b2f(short s) {
  union { unsigned u; float f; } v; v.u = ((unsigned)(unsigned short)s) << 16;
  return v.f;
}
// native-instruction transcendentals (v_exp_f32 / v_rcp_f32)
__device__ inline float fexp(float x) { return __builtin_amdgcn_exp2f(x * 1.4426950408889634f); }
__device__ inline float fsilu(float x) { return x * __builtin_amdgcn_rcpf(1.f + fexp(-x)); }
__device__ inline float fsoftplus(float v) { return (v > 15.f) ? v : __logf(1.f + __expf(v)); }

__device__ inline void gl_lds16(const void* g, void* l) {
  __builtin_amdgcn_global_load_lds((const __attribute__((address_space(1))) void*)g,
                                   (__attribute__((address_space(3))) void*)l, 16, 0, 0);
}

// fp32 -> bf16 convert, 4 elems/thread
__global__ __launch_bounds__(256) void f2bf_k(const float* __restrict__ in,
    short* __restrict__ out, int n4) {
  int i = blockIdx.x * 256 + threadIdx.x;
  if (i >= n4) return;
  float4 v = ((const float4*)in)[i];
  short4 s; s.x = f2b(v.x); s.y = f2b(v.y); s.z = f2b(v.z); s.w = f2b(v.w);
  ((short4*)out)[i] = s;
}

// ---------------- bf16 MFMA GEMM: C = A[M,K](lda) * Bw[N,K](ldb)^T --------
// tile 128x128, BK=32, 4 waves (2x2), each wave 64x64 = 4x4 frags of 16x16x32
// MODE 0: fp32 out; MODE 1: bf16 out; MODE 2: fp32 softplus(acc+bias[n])
template<int MODE>
__global__ __launch_bounds__(256) void gemm_mfma(const short* __restrict__ A,
    const short* __restrict__ Bw, float* __restrict__ Cf, short* __restrict__ Cb,
    int M, int N, int K, int lda, int ldb, int ldc,
    const float* __restrict__ bias) {
  __shared__ alignas(16) short As[128 * 32];
  __shared__ alignas(16) short Bs[128 * 32];
  const int tid = threadIdx.x;
  const int wid = tid >> 6, lane = tid & 63;
  const int row0 = blockIdx.y * 128, col0 = blockIdx.x * 128;
  const int wr = (wid >> 1) * 64, wc = (wid & 1) * 64;
  const int srow = tid >> 2;          // staging row within 64-row round
  const int scol = (tid & 3) * 8;     // staging col (8 bf16 = 16B)
  f32x4 acc[4][4] = {};

  for (int k0 = 0; k0 < K; k0 += 32) {
#pragma unroll
    for (int r = 0; r < 2; ++r) {
      gl_lds16(A  + (long)(row0 + r * 64 + srow) * lda + k0 + scol,
               (short*)((char*)As + r * 4096 + wid * 1024));
      gl_lds16(Bw + (long)(col0 + r * 64 + srow) * ldb + k0 + scol,
               (short*)((char*)Bs + r * 4096 + wid * 1024));
    }
    __syncthreads();
    bf16x8 af[4], bv[4];
#pragma unroll
    for (int i = 0; i < 4; ++i)
      af[i] = *(const bf16x8*)(As + (wr + i * 16 + (lane & 15)) * 32 + (lane >> 4) * 8);
#pragma unroll
    for (int j = 0; j < 4; ++j)
      bv[j] = *(const bf16x8*)(Bs + (wc + j * 16 + (lane & 15)) * 32 + (lane >> 4) * 8);
#pragma unroll
    for (int i = 0; i < 4; ++i)
#pragma unroll
      for (int j = 0; j < 4; ++j)
        acc[i][j] = __builtin_amdgcn_mfma_f32_16x16x32_bf16(af[i], bv[j], acc[i][j], 0, 0, 0);
    __syncthreads();
  }
#pragma unroll
  for (int i = 0; i < 4; ++i) {
#pragma unroll
    for (int j = 0; j < 4; ++j) {
      int gcol = col0 + wc + j * 16 + (lane & 15);
#pragma unroll
      for (int r = 0; r < 4; ++r) {
        int grow = row0 + wr + i * 16 + (lane >> 4) * 4 + r;
        if (MODE == 1) Cb[(long)grow * ldc + gcol] = f2b(acc[i][j][r]);
        else if (MODE == 2) {
          float v = acc[i][j][r] + bias[gcol];
          Cf[(long)grow * ldc + gcol] = fsoftplus(v);
        } else Cf[(long)grow * ldc + gcol] = acc[i][j][r];
      }
    }
  }
}

// ---------------- fp32 vector GEMM (x_proj), split-K ----
__global__ __launch_bounds__(256) void gemm_bt(const float* __restrict__ A,
    const float* __restrict__ Bw, float* __restrict__ C,
    int M, int N, int K, int lda, int ldb, int ldc, int ksplit) {
  __shared__ float As[16][65];
  __shared__ float Bs[16][65];
  int tid = threadIdx.x;
  int tx = tid & 15, ty = tid >> 4;
  int row0 = blockIdx.y * 64;
  int col0 = blockIdx.x * 64;
  int kbeg = blockIdx.z * ksplit;
  int kend = kbeg + ksplit; if (kend > K) kend = K;
  float acc[4][4] = {};
  for (int k0 = kbeg; k0 < kend; k0 += 16) {
#pragma unroll
    for (int i = tid; i < 1024; i += 256) {
      int r = i >> 4, kk = i & 15;
      int gm = row0 + r, gk = k0 + kk;
      As[kk][r] = (gm < M && gk < K) ? A[(long)gm * lda + gk] : 0.f;
      int gn = col0 + r;
      Bs[kk][r] = (gn < N && gk < K) ? Bw[(long)gn * ldb + gk] : 0.f;
    }
    __syncthreads();
#pragma unroll
    for (int kk = 0; kk < 16; ++kk) {
      float a[4], b[4];
#pragma unroll
      for (int j = 0; j < 4; ++j) { a[j] = As[kk][ty * 4 + j]; b[j] = Bs[kk][tx * 4 + j]; }
#pragma unroll
      for (int i = 0; i < 4; ++i)
#pragma unroll
        for (int j = 0; j < 4; ++j)
          acc[i][j] = fmaf(a[i], b[j], acc[i][j]);
    }
    __syncthreads();
  }
#pragma unroll
  for (int i = 0; i < 4; ++i) {
    int gm = row0 + ty * 4 + i;
    if (gm >= M) continue;
#pragma unroll
    for (int j = 0; j < 4; ++j) {
      int gn = col0 + tx * 4 + j;
      if (gn >= N) continue;
      C[((long)blockIdx.z * M + gm) * ldc + gn] = acc[i][j];
    }
  }
}

// sum 8 split-K partials of x_proj; emit fp32 + bf16
__global__ __launch_bounds__(256) void reduce_xp(const float* __restrict__ part,
    float* __restrict__ out, short* __restrict__ outb) {
  int i = blockIdx.x * 256 + threadIdx.x;   // over MROWS*XD
  const int n = MROWS * XD;
  float s = 0.f;
#pragma unroll
  for (int z = 0; z < 8; ++z) s += part[(long)z * n + i];
  out[i] = s;
  outb[i] = f2b(s);
}

// u = silu(causal depthwise conv(xc) + cb), xc = xz[:, 0:DI] (bf16 in)
__global__ __launch_bounds__(256) void conv_silu(const short* __restrict__ xz,
    const float* __restrict__ cw, const float* __restrict__ cb,
    float* __restrict__ u) {
  int idx = blockIdx.x * 256 + threadIdx.x;  // MROWS*DI
  int d = idx & (DI - 1);
  int bt = idx >> 11;
  int t = bt & (TN - 1);
  long rowb = (long)(bt - t);
  float acc = cb[d];
#pragma unroll
  for (int k = 0; k < 4; ++k) {
    int ts = t - 3 + k;
    if (ts >= 0) acc = fmaf(b2f(xz[(rowb + ts) * (2 * DI) + d]), cw[d * 4 + k], acc);
  }
  u[idx] = fsilu(acc);
}

// ---------------- chunked selective scan ----------------
// phase 1: per-chunk local scan (h0=0) + decay product
__global__ __launch_bounds__(256) void scan_p1(const float* __restrict__ dt,
    const float* __restrict__ u, const float* __restrict__ xdbl,
    const float* __restrict__ A_log, float* __restrict__ hloc,
    float* __restrict__ prodb) {
  int tid = threadIdx.x; int n = tid & 15, dl = tid >> 4;
  int bid = blockIdx.x;                 // ((c*BN + b)*128 + dblk)
  int dblk = bid & 127, cb_ = bid >> 7, b = cb_ & 1, c = cb_ >> 1;
  int d = dblk * 16 + dl;
  float Av = -__expf(A_log[d * DS + n]);
  float h = 0.f, sdt = 0.f;
  long row = (long)b * TN + c * CL;
  for (int t = 0; t < CL; ++t) {
    long rw = row + t;
    float dtv = dt[rw * DI + d];
    float uv  = u[rw * DI + d];
    float Bv  = xdbl[rw * XD + RK + n];
    sdt += dtv;
    h = fmaf(fexp(dtv * Av), h, dtv * uv * Bv);
  }
  long o = (((long)c * BN + b) * DI + d) * DS + n;
  hloc[o] = h;
  prodb[o] = fexp(sdt * Av);
}

// phase 2: sequential combine over chunks (per state)
__global__ __launch_bounds__(256) void scan_p2(const float* __restrict__ hloc,
    const float* __restrict__ prodb, float* __restrict__ h0) {
  long idx = blockIdx.x * 256 + threadIdx.x;  // BN*DI*DS = 65536
  float carry = 0.f;
#pragma unroll
  for (int c = 0; c < NC; ++c) {
    long o = (long)c * (BN * DI * DS) + idx;
    h0[o] = carry;
    carry = fmaf(prodb[o], carry, hloc[o]);
  }
}

// phase 3: replay chunk from carried state, emit y (bf16) = (h.C + u*D)*silu(z)
__global__ __launch_bounds__(256) void scan_p3(const float* __restrict__ dt,
    const float* __restrict__ u, const float* __restrict__ xdbl,
    const short* __restrict__ xz, const float* __restrict__ A_log,
    const float* __restrict__ Dskip, const float* __restrict__ h0,
    short* __restrict__ ybf) {
  int tid = threadIdx.x; int n = tid & 15, dl = tid >> 4;
  int bid = blockIdx.x;
  int dblk = bid & 127, cb_ = bid >> 7, b = cb_ & 1, c = cb_ >> 1;
  int d = dblk * 16 + dl;
  float Av = -__expf(A_log[d * DS + n]);
  float Dval = Dskip[d];
  long o = (((long)c * BN + b) * DI + d) * DS + n;
  float h = h0[o];
  long row = (long)b * TN + c * CL;
  for (int t = 0; t < CL; ++t) {
    long rw = row + t;
    float dtv = dt[rw * DI + d];
    float uv  = u[rw * DI + d];
    float Bv  = xdbl[rw * XD + RK + n];
    float Cv  = xdbl[rw * XD + RK + DS + n];
    h = fmaf(fexp(dtv * Av), h, dtv * uv * Bv);
    float py = h * Cv;
    py += __shfl_xor(py, 1);
    py += __shfl_xor(py, 2);
    py += __shfl_xor(py, 4);
    py += __shfl_xor(py, 8);
    if (n == 0) {
      float zv = b2f(xz[rw * (2 * DI) + DI + d]);
      ybf[rw * DI + d] = f2b((py + uv * Dval) * fsilu(zv));
    }
  }
}

// out = LN(h)*w + b + resid ; optional bf16 copy of out
__global__ __launch_bounds__(256) void ln_res(const float* __restrict__ h,
    const float* __restrict__ resid, const float* __restrict__ w,
    const float* __restrict__ bb, float* __restrict__ out, short* __restrict__ ob) {
  int row = blockIdx.x;
  int tid = threadIdx.x;
  const float4* hr = (const float4*)(h + (long)row * DM);
  float4 v = hr[tid];
  __shared__ float sm[256];
  float s = v.x + v.y + v.z + v.w;
  sm[tid] = s; __syncthreads();
  for (int st = 128; st > 0; st >>= 1) { if (tid < st) sm[tid] += sm[tid + st]; __syncthreads(); }
  float mean = sm[0] * (1.f / DM);
  __syncthreads();
  float4 c;
  c.x = v.x - mean; c.y = v.y - mean; c.z = v.z - mean; c.w = v.w - mean;
  float s2 = c.x * c.x + c.y * c.y + c.z * c.z + c.w * c.w;
  sm[tid] = s2; __syncthreads();
  for (int st = 128; st > 0; st >>= 1) { if (tid < st) sm[tid] += sm[tid + st]; __syncthreads(); }
  float inv = rsqrtf(sm[0] * (1.f / DM) + 1e-5f);
  const float4 rv = ((const float4*)(resid + (long)row * DM))[tid];
  const float4 wv = ((const float4*)w)[tid];
  const float4 bv = ((const float4*)bb)[tid];
  float4 ov;
  ov.x = c.x * inv * wv.x + bv.x + rv.x;
  ov.y = c.y * inv * wv.y + bv.y + rv.y;
  ov.z = c.z * inv * wv.z + bv.z + rv.z;
  ov.w = c.w * inv * wv.w + bv.w + rv.w;
  ((float4*)(out + (long)row * DM))[tid] = ov;
  if (ob) {
    short4 sv; sv.x = f2b(ov.x); sv.y = f2b(ov.y); sv.z = f2b(ov.z); sv.w = f2b(ov.w);
    *(short4*)(ob + (long)row * DM + tid * 4) = sv;
  }
}

extern "C" void kernel_launch(void* const* d_in, const int* in_sizes, int n_in,
                              void* d_out, int out_size, void* d_ws, size_t ws_size,
                              hipStream_t stream) {
  const float* x     = (const float*)d_in[0];
  const float* inw   = (const float*)d_in[1];
  const float* convw = (const float*)d_in[2];
  const float* convb = (const float*)d_in[3];
  const float* xpw   = (const float*)d_in[4];
  const float* dtw   = (const float*)d_in[5];
  const float* dtbi  = (const float*)d_in[6];
  const float* alog  = (const float*)d_in[7];
  const float* dsk   = (const float*)d_in[8];
  const float* outw  = (const float*)d_in[9];
  const float* lnw   = (const float*)d_in[10];
  const float* lnb   = (const float*)d_in[11];
  float* outp = (float*)d_out;

  char* w = (char*)d_ws; size_t off = 0;
  auto alloc = [&](size_t bytes) { void* p = w + off; off += (bytes + 255) & ~255ULL; return p; };
  short* inw_bf  = (short*)alloc((size_t)2 * DI * DM * 2);   // per-layer bf16 weights
  short* outw_bf = (short*)alloc((size_t)DM * DI * 2);
  short* dtw_bf  = (short*)alloc((size_t)DI * RK * 2);
  short* abuf    = (short*)alloc((size_t)MROWS * DI * 2);    // xbf / ybf
  short* xzbf    = (short*)alloc((size_t)MROWS * 2 * DI * 2);
  float* ub      = (float*)alloc((size_t)MROWS * DI * 4);
  float* xpart   = (float*)alloc((size_t)8 * MROWS * XD * 4);
  float* xdb     = (float*)alloc((size_t)MROWS * XD * 4);
  short* xdbf    = (short*)alloc((size_t)MROWS * XD * 2);
  float* dtb     = (float*)alloc((size_t)MROWS * DI * 4);
  float* hloc    = (float*)alloc((size_t)NC * BN * DI * DS * 4);
  float* prodb   = (float*)alloc((size_t)NC * BN * DI * DS * 4);
  float* h0      = (float*)alloc((size_t)NC * BN * DI * DS * 4);
  float* hb      = (float*)alloc((size_t)MROWS * DM * 4);
  float* xcur    = (float*)alloc((size_t)MROWS * DM * 4);

  // input x -> bf16
  f2bf_k<<<(MROWS * DM / 4 + 255) / 256, 256, 0, stream>>>(x, abuf, MROWS * DM / 4);

  const float* lin = x;
  for (int l = 0; l < 2; ++l) {
    f2bf_k<<<(2 * DI * DM / 4 + 255) / 256, 256, 0, stream>>>(
        inw + (size_t)l * 2 * DI * DM, inw_bf, 2 * DI * DM / 4);
    f2bf_k<<<(DM * DI / 4 + 255) / 256, 256, 0, stream>>>(
        outw + (size_t)l * DM * DI, outw_bf, DM * DI / 4);
    f2bf_k<<<(DI * RK / 4 + 255) / 256, 256, 0, stream>>>(
        dtw + (size_t)l * DI * RK, dtw_bf, DI * RK / 4);

    // in_proj: [2048,1024] x [4096,1024]^T -> bf16 xz
    gemm_mfma<1><<<dim3((2 * DI) / 128, MROWS / 128), 256, 0, stream>>>(
        abuf, inw_bf, nullptr, xzbf, MROWS, 2 * DI, DM, DM, DM, 2 * DI, nullptr);

    conv_silu<<<(MROWS * DI) / 256, 256, 0, stream>>>(
        xzbf, convw + (size_t)l * DI * 4, convb + (size_t)l * DI, ub);

    // x_proj: split-K=8 fp32
    gemm_bt<<<dim3(2, MROWS / 64, 8), 256, 0, stream>>>(ub,
        xpw + (size_t)l * XD * DI, xpart, MROWS, XD, DI, DI, DI, XD, DI / 8);
    reduce_xp<<<(MROWS * XD) / 256, 256, 0, stream>>>(xpart, xdb, xdbf);

    // dt_proj + softplus (MFMA, K=64)
    gemm_mfma<2><<<dim3(DI / 128, MROWS / 128), 256, 0, stream>>>(
        xdbf, dtw_bf, dtb, nullptr, MROWS, DI, RK, XD, RK, DI,
        dtbi + (size_t)l * DI);

    // chunked scan
    scan_p1<<<NC * BN * (DI / 16), 256, 0, stream>>>(dtb, ub, xdb,
        alog + (size_t)l * DI * DS, hloc, prodb);
    scan_p2<<<(BN * DI * DS) / 256, 256, 0, stream>>>(hloc, prodb, h0);
    scan_p3<<<NC * BN * (DI / 16), 256, 0, stream>>>(dtb, ub, xdb, xzbf,
        alog + (size_t)l * DI * DS, dsk + (size_t)l * DI, h0, abuf);

    // out_proj: [2048,2048] x [1024,2048]^T -> fp32 hb
    gemm_mfma<0><<<dim3(DM / 128, MROWS / 128), 256, 0, stream>>>(
        abuf, outw_bf, hb, nullptr, MROWS, DM, DI, DI, DI, DM, nullptr);

    float* lo = (l == 0) ? xcur : outp;
    short* lob = (l == 0) ? abuf : nullptr;
    ln_res<<<MROWS, 256, 0, stream>>>(hb, lin,
        lnw + (size_t)l * DM, lnb + (size_t)l * DM, lo, lob);
    lin = xcur;
  }
}

// Round 4
// 447.102 us; speedup vs baseline: 8.3278x; 1.3789x over previous
//
#include <hip/hip_runtime.h>

constexpr int BN = 2;       // batch
constexpr int TN = 1024;    // seq len
constexpr int DM = 1024;    // d_model
constexpr int DI = 2048;    // d_inner
constexpr int DS = 16;      // d_state
constexpr int RK = 64;      // dt_rank
constexpr int XD = 96;      // dt_rank + 2*d_state
constexpr int MROWS = BN * TN; // 2048
constexpr int NC = 64;      // scan chunks
constexpr int CL = 16;      // chunk length (NC*CL == TN)

using f32x4  = __attribute__((ext_vector_type(4))) float;
using bf16x8 = __attribute__((ext_vector_type(8))) short;

__device__ inline short f2b(float f) {
  union { float f; unsigned u; } v; v.f = f;
  unsigned r = (v.u + 0x7FFFu + ((v.u >> 16) & 1u)) >> 16;
  return (short)r;
}
__device__ inline float b2f(short s) {
  union { unsigned u; float f; } v; v.u = ((unsigned)(unsigned short)s) << 16;
  return v.f;
}
// native-instruction transcendentals (v_exp_f32 / v_rcp_f32)
__device__ inline float fexp(float x) { return __builtin_amdgcn_exp2f(x * 1.4426950408889634f); }
__device__ inline float fsilu(float x) { return x * __builtin_amdgcn_rcpf(1.f + fexp(-x)); }
__device__ inline float fsoftplus(float v) { return (v > 15.f) ? v : __logf(1.f + __expf(v)); }

__device__ inline void gl_lds16(const void* g, void* l) {
  __builtin_amdgcn_global_load_lds((const __attribute__((address_space(1))) void*)g,
                                   (__attribute__((address_space(3))) void*)l, 16, 0, 0);
}

// fp32 -> bf16 convert, 4 elems/thread
__global__ __launch_bounds__(256) void f2bf_k(const float* __restrict__ in,
    short* __restrict__ out, int n4) {
  int i = blockIdx.x * 256 + threadIdx.x;
  if (i >= n4) return;
  float4 v = ((const float4*)in)[i];
  short4 s; s.x = f2b(v.x); s.y = f2b(v.y); s.z = f2b(v.z); s.w = f2b(v.w);
  ((short4*)out)[i] = s;
}

// ---------------- bf16 MFMA GEMM: C = A[M,K](lda) * Bw[N,K](ldb)^T --------
// tile 128x128, BK=32, 4 waves (2x2), each wave 64x64 = 4x4 frags of 16x16x32
// MODE 0: fp32 out; MODE 1: bf16 out; MODE 2: fp32 softplus(acc+bias[n])
template<int MODE>
__global__ __launch_bounds__(256) void gemm_mfma(const short* __restrict__ A,
    const short* __restrict__ Bw, float* __restrict__ Cf, short* __restrict__ Cb,
    int M, int N, int K, int lda, int ldb, int ldc,
    const float* __restrict__ bias) {
  __shared__ alignas(16) short As[128 * 32];
  __shared__ alignas(16) short Bs[128 * 32];
  const int tid = threadIdx.x;
  const int wid = tid >> 6, lane = tid & 63;
  const int row0 = blockIdx.y * 128, col0 = blockIdx.x * 128;
  const int wr = (wid >> 1) * 64, wc = (wid & 1) * 64;
  const int srow = tid >> 2;          // staging row within 64-row round
  const int scol = (tid & 3) * 8;     // staging col (8 bf16 = 16B)
  f32x4 acc[4][4] = {};

  for (int k0 = 0; k0 < K; k0 += 32) {
#pragma unroll
    for (int r = 0; r < 2; ++r) {
      gl_lds16(A  + (long)(row0 + r * 64 + srow) * lda + k0 + scol,
               (short*)((char*)As + r * 4096 + wid * 1024));
      gl_lds16(Bw + (long)(col0 + r * 64 + srow) * ldb + k0 + scol,
               (short*)((char*)Bs + r * 4096 + wid * 1024));
    }
    __syncthreads();
    bf16x8 af[4], bv[4];
#pragma unroll
    for (int i = 0; i < 4; ++i)
      af[i] = *(const bf16x8*)(As + (wr + i * 16 + (lane & 15)) * 32 + (lane >> 4) * 8);
#pragma unroll
    for (int j = 0; j < 4; ++j)
      bv[j] = *(const bf16x8*)(Bs + (wc + j * 16 + (lane & 15)) * 32 + (lane >> 4) * 8);
#pragma unroll
    for (int i = 0; i < 4; ++i)
#pragma unroll
      for (int j = 0; j < 4; ++j)
        acc[i][j] = __builtin_amdgcn_mfma_f32_16x16x32_bf16(af[i], bv[j], acc[i][j], 0, 0, 0);
    __syncthreads();
  }
#pragma unroll
  for (int i = 0; i < 4; ++i) {
#pragma unroll
    for (int j = 0; j < 4; ++j) {
      int gcol = col0 + wc + j * 16 + (lane & 15);
#pragma unroll
      for (int r = 0; r < 4; ++r) {
        int grow = row0 + wr + i * 16 + (lane >> 4) * 4 + r;
        if (MODE == 1) Cb[(long)grow * ldc + gcol] = f2b(acc[i][j][r]);
        else if (MODE == 2) {
          float v = acc[i][j][r] + bias[gcol];
          Cf[(long)grow * ldc + gcol] = fsoftplus(v);
        } else Cf[(long)grow * ldc + gcol] = acc[i][j][r];
      }
    }
  }
}

// ---------------- fp32 vector GEMM (x_proj), split-K ----
__global__ __launch_bounds__(256) void gemm_bt(const float* __restrict__ A,
    const float* __restrict__ Bw, float* __restrict__ C,
    int M, int N, int K, int lda, int ldb, int ldc, int ksplit) {
  __shared__ float As[16][65];
  __shared__ float Bs[16][65];
  int tid = threadIdx.x;
  int tx = tid & 15, ty = tid >> 4;
  int row0 = blockIdx.y * 64;
  int col0 = blockIdx.x * 64;
  int kbeg = blockIdx.z * ksplit;
  int kend = kbeg + ksplit; if (kend > K) kend = K;
  float acc[4][4] = {};
  for (int k0 = kbeg; k0 < kend; k0 += 16) {
#pragma unroll
    for (int i = tid; i < 1024; i += 256) {
      int r = i >> 4, kk = i & 15;
      int gm = row0 + r, gk = k0 + kk;
      As[kk][r] = (gm < M && gk < K) ? A[(long)gm * lda + gk] : 0.f;
      int gn = col0 + r;
      Bs[kk][r] = (gn < N && gk < K) ? Bw[(long)gn * ldb + gk] : 0.f;
    }
    __syncthreads();
#pragma unroll
    for (int kk = 0; kk < 16; ++kk) {
      float a[4], b[4];
#pragma unroll
      for (int j = 0; j < 4; ++j) { a[j] = As[kk][ty * 4 + j]; b[j] = Bs[kk][tx * 4 + j]; }
#pragma unroll
      for (int i = 0; i < 4; ++i)
#pragma unroll
        for (int j = 0; j < 4; ++j)
          acc[i][j] = fmaf(a[i], b[j], acc[i][j]);
    }
    __syncthreads();
  }
#pragma unroll
  for (int i = 0; i < 4; ++i) {
    int gm = row0 + ty * 4 + i;
    if (gm >= M) continue;
#pragma unroll
    for (int j = 0; j < 4; ++j) {
      int gn = col0 + tx * 4 + j;
      if (gn >= N) continue;
      C[((long)blockIdx.z * M + gm) * ldc + gn] = acc[i][j];
    }
  }
}

// sum 8 split-K partials of x_proj; emit fp32 + bf16
__global__ __launch_bounds__(256) void reduce_xp(const float* __restrict__ part,
    float* __restrict__ out, short* __restrict__ outb) {
  int i = blockIdx.x * 256 + threadIdx.x;   // over MROWS*XD
  const int n = MROWS * XD;
  float s = 0.f;
#pragma unroll
  for (int z = 0; z < 8; ++z) s += part[(long)z * n + i];
  out[i] = s;
  outb[i] = f2b(s);
}

// u = silu(causal depthwise conv(xc) + cb), xc = xz[:, 0:DI] (bf16 in)
__global__ __launch_bounds__(256) void conv_silu(const short* __restrict__ xz,
    const float* __restrict__ cw, const float* __restrict__ cb,
    float* __restrict__ u) {
  int idx = blockIdx.x * 256 + threadIdx.x;  // MROWS*DI
  int d = idx & (DI - 1);
  int bt = idx >> 11;
  int t = bt & (TN - 1);
  long rowb = (long)(bt - t);
  float acc = cb[d];
#pragma unroll
  for (int k = 0; k < 4; ++k) {
    int ts = t - 3 + k;
    if (ts >= 0) acc = fmaf(b2f(xz[(rowb + ts) * (2 * DI) + d]), cw[d * 4 + k], acc);
  }
  u[idx] = fsilu(acc);
}

// ---------------- chunked selective scan (channel-per-thread) ----------------
// thread = one (b,d) channel within one chunk; all 16 states in registers.
// B/C rows are wave-uniform float4 broadcast loads. No shuffles.
// phase 1: local scan (h0=0) -> hloc, decay product -> prodb
__global__ __launch_bounds__(256) void scan_p1(const float* __restrict__ dt,
    const float* __restrict__ u, const float* __restrict__ xdbl,
    const float* __restrict__ A_log, float* __restrict__ hloc,
    float* __restrict__ prodb) {
  int tid = threadIdx.x;
  int bid = blockIdx.x;              // ((c*BN + b)*8 + dblk)
  int dblk = bid & 7, cb_ = bid >> 3, b = cb_ & 1, c = cb_ >> 1;
  int d = dblk * 256 + tid;
  float Av[16];
  {
    const float4* Ap = (const float4*)(A_log + (long)d * DS);
#pragma unroll
    for (int q = 0; q < 4; ++q) {
      float4 a = Ap[q];
      Av[4*q+0] = -__expf(a.x); Av[4*q+1] = -__expf(a.y);
      Av[4*q+2] = -__expf(a.z); Av[4*q+3] = -__expf(a.w);
    }
  }
  float h[16] = {};
  float sdt = 0.f;
  long row = (long)b * TN + c * CL;
  for (int t = 0; t < CL; ++t) {
    long rw = row + t;
    float dtv = dt[rw * DI + d];
    float uv  = u [rw * DI + d];
    float du = dtv * uv;
    sdt += dtv;
    const float4* Bp = (const float4*)(xdbl + rw * XD + RK);
#pragma unroll
    for (int q = 0; q < 4; ++q) {
      float4 Bv = Bp[q];
      h[4*q+0] = fmaf(fexp(dtv * Av[4*q+0]), h[4*q+0], du * Bv.x);
      h[4*q+1] = fmaf(fexp(dtv * Av[4*q+1]), h[4*q+1], du * Bv.y);
      h[4*q+2] = fmaf(fexp(dtv * Av[4*q+2]), h[4*q+2], du * Bv.z);
      h[4*q+3] = fmaf(fexp(dtv * Av[4*q+3]), h[4*q+3], du * Bv.w);
    }
  }
  long o = (((long)c * BN + b) * DI + d) * DS;
  float4* hp = (float4*)(hloc + o);
  float4* pp = (float4*)(prodb + o);
#pragma unroll
  for (int q = 0; q < 4; ++q) {
    float4 hv; hv.x = h[4*q]; hv.y = h[4*q+1]; hv.z = h[4*q+2]; hv.w = h[4*q+3];
    hp[q] = hv;
    float4 pv;
    pv.x = fexp(sdt * Av[4*q+0]); pv.y = fexp(sdt * Av[4*q+1]);
    pv.z = fexp(sdt * Av[4*q+2]); pv.w = fexp(sdt * Av[4*q+3]);
    pp[q] = pv;
  }
}

// phase 2: sequential combine over chunks (per state)
__global__ __launch_bounds__(256) void scan_p2(const float* __restrict__ hloc,
    const float* __restrict__ prodb, float* __restrict__ h0) {
  long idx = blockIdx.x * 256 + threadIdx.x;  // BN*DI*DS = 65536
  float carry = 0.f;
  for (int c = 0; c < NC; ++c) {
    long o = (long)c * (BN * DI * DS) + idx;
    h0[o] = carry;
    carry = fmaf(prodb[o], carry, hloc[o]);
  }
}

// phase 3: replay chunk from carried state; y = (h.C + u*D)*silu(z) -> bf16
__global__ __launch_bounds__(256) void scan_p3(const float* __restrict__ dt,
    const float* __restrict__ u, const float* __restrict__ xdbl,
    const short* __restrict__ xz, const float* __restrict__ A_log,
    const float* __restrict__ Dskip, const float* __restrict__ h0,
    short* __restrict__ ybf) {
  int tid = threadIdx.x;
  int bid = blockIdx.x;
  int dblk = bid & 7, cb_ = bid >> 3, b = cb_ & 1, c = cb_ >> 1;
  int d = dblk * 256 + tid;
  float Av[16];
  {
    const float4* Ap = (const float4*)(A_log + (long)d * DS);
#pragma unroll
    for (int q = 0; q < 4; ++q) {
      float4 a = Ap[q];
      Av[4*q+0] = -__expf(a.x); Av[4*q+1] = -__expf(a.y);
      Av[4*q+2] = -__expf(a.z); Av[4*q+3] = -__expf(a.w);
    }
  }
  float Dval = Dskip[d];
  float h[16];
  {
    const float4* hp = (const float4*)(h0 + (((long)c * BN + b) * DI + d) * DS);
#pragma unroll
    for (int q = 0; q < 4; ++q) {
      float4 hv = hp[q];
      h[4*q] = hv.x; h[4*q+1] = hv.y; h[4*q+2] = hv.z; h[4*q+3] = hv.w;
    }
  }
  long row = (long)b * TN + c * CL;
  for (int t = 0; t < CL; ++t) {
    long rw = row + t;
    float dtv = dt[rw * DI + d];
    float uv  = u [rw * DI + d];
    float du = dtv * uv;
    const float4* Bp = (const float4*)(xdbl + rw * XD + RK);
    const float4* Cp = (const float4*)(xdbl + rw * XD + RK + DS);
    float y = 0.f;
#pragma unroll
    for (int q = 0; q < 4; ++q) {
      float4 Bv = Bp[q];
      float4 Cv = Cp[q];
      h[4*q+0] = fmaf(fexp(dtv * Av[4*q+0]), h[4*q+0], du * Bv.x);
      h[4*q+1] = fmaf(fexp(dtv * Av[4*q+1]), h[4*q+1], du * Bv.y);
      h[4*q+2] = fmaf(fexp(dtv * Av[4*q+2]), h[4*q+2], du * Bv.z);
      h[4*q+3] = fmaf(fexp(dtv * Av[4*q+3]), h[4*q+3], du * Bv.w);
      y = fmaf(h[4*q+0], Cv.x, y);
      y = fmaf(h[4*q+1], Cv.y, y);
      y = fmaf(h[4*q+2], Cv.z, y);
      y = fmaf(h[4*q+3], Cv.w, y);
    }
    float zv = b2f(xz[rw * (2 * DI) + DI + d]);
    ybf[rw * DI + d] = f2b((y + uv * Dval) * fsilu(zv));
  }
}

// out = LN(h)*w + b + resid ; optional bf16 copy of out
__global__ __launch_bounds__(256) void ln_res(const float* __restrict__ h,
    const float* __restrict__ resid, const float* __restrict__ w,
    const float* __restrict__ bb, float* __restrict__ out, short* __restrict__ ob) {
  int row = blockIdx.x;
  int tid = threadIdx.x;
  const float4* hr = (const float4*)(h + (long)row * DM);
  float4 v = hr[tid];
  __shared__ float sm[256];
  float s = v.x + v.y + v.z + v.w;
  sm[tid] = s; __syncthreads();
  for (int st = 128; st > 0; st >>= 1) { if (tid < st) sm[tid] += sm[tid + st]; __syncthreads(); }
  float mean = sm[0] * (1.f / DM);
  __syncthreads();
  float4 c;
  c.x = v.x - mean; c.y = v.y - mean; c.z = v.z - mean; c.w = v.w - mean;
  float s2 = c.x * c.x + c.y * c.y + c.z * c.z + c.w * c.w;
  sm[tid] = s2; __syncthreads();
  for (int st = 128; st > 0; st >>= 1) { if (tid < st) sm[tid] += sm[tid + st]; __syncthreads(); }
  float inv = rsqrtf(sm[0] * (1.f / DM) + 1e-5f);
  const float4 rv = ((const float4*)(resid + (long)row * DM))[tid];
  const float4 wv = ((const float4*)w)[tid];
  const float4 bv = ((const float4*)bb)[tid];
  float4 ov;
  ov.x = c.x * inv * wv.x + bv.x + rv.x;
  ov.y = c.y * inv * wv.y + bv.y + rv.y;
  ov.z = c.z * inv * wv.z + bv.z + rv.z;
  ov.w = c.w * inv * wv.w + bv.w + rv.w;
  ((float4*)(out + (long)row * DM))[tid] = ov;
  if (ob) {
    short4 sv; sv.x = f2b(ov.x); sv.y = f2b(ov.y); sv.z = f2b(ov.z); sv.w = f2b(ov.w);
    *(short4*)(ob + (long)row * DM + tid * 4) = sv;
  }
}

extern "C" void kernel_launch(void* const* d_in, const int* in_sizes, int n_in,
                              void* d_out, int out_size, void* d_ws, size_t ws_size,
                              hipStream_t stream) {
  const float* x     = (const float*)d_in[0];
  const float* inw   = (const float*)d_in[1];
  const float* convw = (const float*)d_in[2];
  const float* convb = (const float*)d_in[3];
  const float* xpw   = (const float*)d_in[4];
  const float* dtw   = (const float*)d_in[5];
  const float* dtbi  = (const float*)d_in[6];
  const float* alog  = (const float*)d_in[7];
  const float* dsk   = (const float*)d_in[8];
  const float* outw  = (const float*)d_in[9];
  const float* lnw   = (const float*)d_in[10];
  const float* lnb   = (const float*)d_in[11];
  float* outp = (float*)d_out;

  char* w = (char*)d_ws; size_t off = 0;
  auto alloc = [&](size_t bytes) { void* p = w + off; off += (bytes + 255) & ~255ULL; return p; };
  short* inw_bf  = (short*)alloc((size_t)2 * DI * DM * 2);   // per-layer bf16 weights
  short* outw_bf = (short*)alloc((size_t)DM * DI * 2);
  short* dtw_bf  = (short*)alloc((size_t)DI * RK * 2);
  short* abuf    = (short*)alloc((size_t)MROWS * DI * 2);    // xbf / ybf
  short* xzbf    = (short*)alloc((size_t)MROWS * 2 * DI * 2);
  float* ub      = (float*)alloc((size_t)MROWS * DI * 4);
  float* xpart   = (float*)alloc((size_t)8 * MROWS * XD * 4);
  float* xdb     = (float*)alloc((size_t)MROWS * XD * 4);
  short* xdbf    = (short*)alloc((size_t)MROWS * XD * 2);
  float* dtb     = (float*)alloc((size_t)MROWS * DI * 4);
  float* hloc    = (float*)alloc((size_t)NC * BN * DI * DS * 4);
  float* prodb   = (float*)alloc((size_t)NC * BN * DI * DS * 4);
  float* h0      = (float*)alloc((size_t)NC * BN * DI * DS * 4);
  float* hb      = (float*)alloc((size_t)MROWS * DM * 4);
  float* xcur    = (float*)alloc((size_t)MROWS * DM * 4);

  // input x -> bf16
  f2bf_k<<<(MROWS * DM / 4 + 255) / 256, 256, 0, stream>>>(x, abuf, MROWS * DM / 4);

  const float* lin = x;
  for (int l = 0; l < 2; ++l) {
    f2bf_k<<<(2 * DI * DM / 4 + 255) / 256, 256, 0, stream>>>(
        inw + (size_t)l * 2 * DI * DM, inw_bf, 2 * DI * DM / 4);
    f2bf_k<<<(DM * DI / 4 + 255) / 256, 256, 0, stream>>>(
        outw + (size_t)l * DM * DI, outw_bf, DM * DI / 4);
    f2bf_k<<<(DI * RK / 4 + 255) / 256, 256, 0, stream>>>(
        dtw + (size_t)l * DI * RK, dtw_bf, DI * RK / 4);

    // in_proj: [2048,1024] x [4096,1024]^T -> bf16 xz
    gemm_mfma<1><<<dim3((2 * DI) / 128, MROWS / 128), 256, 0, stream>>>(
        abuf, inw_bf, nullptr, xzbf, MROWS, 2 * DI, DM, DM, DM, 2 * DI, nullptr);

    conv_silu<<<(MROWS * DI) / 256, 256, 0, stream>>>(
        xzbf, convw + (size_t)l * DI * 4, convb + (size_t)l * DI, ub);

    // x_proj: split-K=8 fp32
    gemm_bt<<<dim3(2, MROWS / 64, 8), 256, 0, stream>>>(ub,
        xpw + (size_t)l * XD * DI, xpart, MROWS, XD, DI, DI, DI, XD, DI / 8);
    reduce_xp<<<(MROWS * XD) / 256, 256, 0, stream>>>(xpart, xdb, xdbf);

    // dt_proj + softplus (MFMA, K=64)
    gemm_mfma<2><<<dim3(DI / 128, MROWS / 128), 256, 0, stream>>>(
        xdbf, dtw_bf, dtb, nullptr, MROWS, DI, RK, XD, RK, DI,
        dtbi + (size_t)l * DI);

    // chunked scan (channel-per-thread)
    scan_p1<<<NC * BN * (DI / 256), 256, 0, stream>>>(dtb, ub, xdb,
        alog + (size_t)l * DI * DS, hloc, prodb);
    scan_p2<<<(BN * DI * DS) / 256, 256, 0, stream>>>(hloc, prodb, h0);
    scan_p3<<<NC * BN * (DI / 256), 256, 0, stream>>>(dtb, ub, xdb, xzbf,
        alog + (size_t)l * DI * DS, dsk + (size_t)l * DI, h0, abuf);

    // out_proj: [2048,2048] x [1024,2048]^T -> fp32 hb
    gemm_mfma<0><<<dim3(DM / 128, MROWS / 128), 256, 0, stream>>>(
        abuf, outw_bf, hb, nullptr, MROWS, DM, DI, DI, DI, DM, nullptr);

    float* lo = (l == 0) ? xcur : outp;
    short* lob = (l == 0) ? abuf : nullptr;
    ln_res<<<MROWS, 256, 0, stream>>>(hb, lin,
        lnw + (size_t)l * DM, lnb + (size_t)l * DM, lo, lob);
    lin = xcur;
  }
}

// Round 5
// 375.383 us; speedup vs baseline: 9.9188x; 1.1911x over previous
//
#include <hip/hip_runtime.h>

constexpr int BN = 2;       // batch
constexpr int TN = 1024;    // seq len
constexpr int DM = 1024;    // d_model
constexpr int DI = 2048;    // d_inner
constexpr int DS = 16;      // d_state
constexpr int RK = 64;      // dt_rank
constexpr int XD = 96;      // dt_rank + 2*d_state
constexpr int XDP = 128;    // padded x_dbl stride
constexpr int MROWS = BN * TN; // 2048
constexpr int NC = 32;      // scan chunks
constexpr int CL = 32;      // chunk length (NC*CL == TN)
constexpr int XPZ = 8;      // x_proj split-K factor

using f32x4  = __attribute__((ext_vector_type(4))) float;
using bf16x8 = __attribute__((ext_vector_type(8))) short;

__device__ inline short f2b(float f) {
  union { float f; unsigned u; } v; v.f = f;
  unsigned r = (v.u + 0x7FFFu + ((v.u >> 16) & 1u)) >> 16;
  return (short)r;
}
__device__ inline float b2f(short s) {
  union { unsigned u; float f; } v; v.u = ((unsigned)(unsigned short)s) << 16;
  return v.f;
}
// native-instruction transcendentals (v_exp_f32 / v_rcp_f32)
__device__ inline float fexp(float x) { return __builtin_amdgcn_exp2f(x * 1.4426950408889634f); }
__device__ inline float fsilu(float x) { return x * __builtin_amdgcn_rcpf(1.f + fexp(-x)); }
__device__ inline float fsoftplus(float v) { return (v > 15.f) ? v : __logf(1.f + __expf(v)); }

__device__ inline void gl_lds16(const void* g, void* l) {
  __builtin_amdgcn_global_load_lds((const __attribute__((address_space(1))) void*)g,
                                   (__attribute__((address_space(3))) void*)l, 16, 0, 0);
}

// fp32 -> bf16 convert, 4 elems/thread
__global__ __launch_bounds__(256) void f2bf_k(const float* __restrict__ in,
    short* __restrict__ out, int n4) {
  int i = blockIdx.x * 256 + threadIdx.x;
  if (i >= n4) return;
  float4 v = ((const float4*)in)[i];
  short4 s; s.x = f2b(v.x); s.y = f2b(v.y); s.z = f2b(v.z); s.w = f2b(v.w);
  ((short4*)out)[i] = s;
}

// x_proj weight [L][XD][DI] fp32 -> padded [L][XDP][DI] bf16 (rows >= XD zero)
__global__ __launch_bounds__(256) void xpw_pad_k(const float* __restrict__ in,
    short* __restrict__ out) {
  int i = blockIdx.x * 256 + threadIdx.x;        // over 2*XDP*DI/4
  int c4 = i & (DI / 4 - 1);
  int rl = i >> 9;                                // row + layer*XDP
  int r = rl & (XDP - 1), l = rl >> 7;
  short4 s;
  if (r < XD) {
    float4 v = ((const float4*)(in + ((long)l * XD + r) * DI))[c4];
    s.x = f2b(v.x); s.y = f2b(v.y); s.z = f2b(v.z); s.w = f2b(v.w);
  } else { s.x = s.y = s.z = s.w = 0; }
  ((short4*)(out + ((long)l * XDP + r) * DI))[c4] = s;
}

// ---------------- bf16 MFMA GEMM: C = A[M,K](lda) * Bw[N,K](ldb)^T --------
// tile 128x128, BK=32, 4 waves (2x2), each wave 64x64 = 4x4 frags of 16x16x32
// MODE 0: fp32 out; MODE 1: bf16 out; MODE 2: fp32 softplus(acc+bias[n])
// KS 1: split-K over blockIdx.z (ksplit per z), partial out at z*M*ldc
template<int MODE, int KS>
__global__ __launch_bounds__(256) void gemm_mfma(const short* __restrict__ A,
    const short* __restrict__ Bw, float* __restrict__ Cf, short* __restrict__ Cb,
    int M, int N, int K, int lda, int ldb, int ldc,
    const float* __restrict__ bias, int ksplit) {
  __shared__ alignas(16) short As[128 * 32];
  __shared__ alignas(16) short Bs[128 * 32];
  const int tid = threadIdx.x;
  const int wid = tid >> 6, lane = tid & 63;
  const int row0 = blockIdx.y * 128, col0 = blockIdx.x * 128;
  const int wr = (wid >> 1) * 64, wc = (wid & 1) * 64;
  const int srow = tid >> 2;          // staging row within 64-row round
  const int scol = (tid & 3) * 8;     // staging col (8 bf16 = 16B)
  f32x4 acc[4][4] = {};
  const int kbeg = KS ? blockIdx.z * ksplit : 0;
  const int kend = KS ? kbeg + ksplit : K;

  for (int k0 = kbeg; k0 < kend; k0 += 32) {
#pragma unroll
    for (int r = 0; r < 2; ++r) {
      gl_lds16(A  + (long)(row0 + r * 64 + srow) * lda + k0 + scol,
               (short*)((char*)As + r * 4096 + wid * 1024));
      gl_lds16(Bw + (long)(col0 + r * 64 + srow) * ldb + k0 + scol,
               (short*)((char*)Bs + r * 4096 + wid * 1024));
    }
    __syncthreads();
    bf16x8 af[4], bv[4];
#pragma unroll
    for (int i = 0; i < 4; ++i)
      af[i] = *(const bf16x8*)(As + (wr + i * 16 + (lane & 15)) * 32 + (lane >> 4) * 8);
#pragma unroll
    for (int j = 0; j < 4; ++j)
      bv[j] = *(const bf16x8*)(Bs + (wc + j * 16 + (lane & 15)) * 32 + (lane >> 4) * 8);
#pragma unroll
    for (int i = 0; i < 4; ++i)
#pragma unroll
      for (int j = 0; j < 4; ++j)
        acc[i][j] = __builtin_amdgcn_mfma_f32_16x16x32_bf16(af[i], bv[j], acc[i][j], 0, 0, 0);
    __syncthreads();
  }
  const long zbase = KS ? (long)blockIdx.z * M * ldc : 0;
#pragma unroll
  for (int i = 0; i < 4; ++i) {
#pragma unroll
    for (int j = 0; j < 4; ++j) {
      int gcol = col0 + wc + j * 16 + (lane & 15);
#pragma unroll
      for (int r = 0; r < 4; ++r) {
        int grow = row0 + wr + i * 16 + (lane >> 4) * 4 + r;
        if (MODE == 1) Cb[(long)grow * ldc + gcol] = f2b(acc[i][j][r]);
        else if (MODE == 2) {
          float v = acc[i][j][r] + bias[gcol];
          Cf[(long)grow * ldc + gcol] = fsoftplus(v);
        } else Cf[zbase + (long)grow * ldc + gcol] = acc[i][j][r];
      }
    }
  }
}

// sum XPZ split-K partials of x_proj; emit fp32 (stride XDP) + bf16
__global__ __launch_bounds__(256) void reduce_xp(const float* __restrict__ part,
    float* __restrict__ out, short* __restrict__ outb) {
  int i = blockIdx.x * 256 + threadIdx.x;   // over MROWS*XDP
  const int n = MROWS * XDP;
  float s = 0.f;
#pragma unroll
  for (int z = 0; z < XPZ; ++z) s += part[(long)z * n + i];
  out[i] = s;
  outb[i] = f2b(s);
}

// u = silu(causal depthwise conv(xc) + cb); fp32 + bf16 out
__global__ __launch_bounds__(256) void conv_silu(const short* __restrict__ xz,
    const float* __restrict__ cw, const float* __restrict__ cb,
    float* __restrict__ u, short* __restrict__ ubf) {
  int idx = blockIdx.x * 256 + threadIdx.x;  // MROWS*DI
  int d = idx & (DI - 1);
  int bt = idx >> 11;
  int t = bt & (TN - 1);
  long rowb = (long)(bt - t);
  float acc = cb[d];
#pragma unroll
  for (int k = 0; k < 4; ++k) {
    int ts = t - 3 + k;
    if (ts >= 0) acc = fmaf(b2f(xz[(rowb + ts) * (2 * DI) + d]), cw[d * 4 + k], acc);
  }
  float v = fsilu(acc);
  u[idx] = v;
  ubf[idx] = f2b(v);
}

// ---------------- chunked selective scan (channel-per-thread) ----------------
// phase 1: local scan (h0=0) -> hloc, decay product -> prodb
__global__ __launch_bounds__(256) void scan_p1(const float* __restrict__ dt,
    const float* __restrict__ u, const float* __restrict__ xdbl,
    const float* __restrict__ A_log, float* __restrict__ hloc,
    float* __restrict__ prodb) {
  int tid = threadIdx.x;
  int bid = blockIdx.x;              // ((c*BN + b)*8 + dblk)
  int dblk = bid & 7, cb_ = bid >> 3, b = cb_ & 1, c = cb_ >> 1;
  int d = dblk * 256 + tid;
  float Av[16];
  {
    const float4* Ap = (const float4*)(A_log + (long)d * DS);
#pragma unroll
    for (int q = 0; q < 4; ++q) {
      float4 a = Ap[q];
      Av[4*q+0] = -__expf(a.x); Av[4*q+1] = -__expf(a.y);
      Av[4*q+2] = -__expf(a.z); Av[4*q+3] = -__expf(a.w);
    }
  }
  float h[16] = {};
  float sdt = 0.f;
  long row = (long)b * TN + c * CL;
  for (int t = 0; t < CL; ++t) {
    long rw = row + t;
    float dtv = dt[rw * DI + d];
    float uv  = u [rw * DI + d];
    float du = dtv * uv;
    sdt += dtv;
    const float4* Bp = (const float4*)(xdbl + rw * XDP + RK);
#pragma unroll
    for (int q = 0; q < 4; ++q) {
      float4 Bv = Bp[q];
      h[4*q+0] = fmaf(fexp(dtv * Av[4*q+0]), h[4*q+0], du * Bv.x);
      h[4*q+1] = fmaf(fexp(dtv * Av[4*q+1]), h[4*q+1], du * Bv.y);
      h[4*q+2] = fmaf(fexp(dtv * Av[4*q+2]), h[4*q+2], du * Bv.z);
      h[4*q+3] = fmaf(fexp(dtv * Av[4*q+3]), h[4*q+3], du * Bv.w);
    }
  }
  long o = (((long)c * BN + b) * DI + d) * DS;
  float4* hp = (float4*)(hloc + o);
  float4* pp = (float4*)(prodb + o);
#pragma unroll
  for (int q = 0; q < 4; ++q) {
    float4 hv; hv.x = h[4*q]; hv.y = h[4*q+1]; hv.z = h[4*q+2]; hv.w = h[4*q+3];
    hp[q] = hv;
    float4 pv;
    pv.x = fexp(sdt * Av[4*q+0]); pv.y = fexp(sdt * Av[4*q+1]);
    pv.z = fexp(sdt * Av[4*q+2]); pv.w = fexp(sdt * Av[4*q+3]);
    pp[q] = pv;
  }
}

// phase 2: sequential combine over chunks (per state)
__global__ __launch_bounds__(256) void scan_p2(const float* __restrict__ hloc,
    const float* __restrict__ prodb, float* __restrict__ h0) {
  long idx = blockIdx.x * 256 + threadIdx.x;  // BN*DI*DS = 65536
  float carry = 0.f;
  for (int c = 0; c < NC; ++c) {
    long o = (long)c * (BN * DI * DS) + idx;
    h0[o] = carry;
    carry = fmaf(prodb[o], carry, hloc[o]);
  }
}

// phase 3: replay chunk from carried state; y = (h.C + u*D)*silu(z) -> bf16
__global__ __launch_bounds__(256) void scan_p3(const float* __restrict__ dt,
    const float* __restrict__ u, const float* __restrict__ xdbl,
    const short* __restrict__ xz, const float* __restrict__ A_log,
    const float* __restrict__ Dskip, const float* __restrict__ h0,
    short* __restrict__ ybf) {
  int tid = threadIdx.x;
  int bid = blockIdx.x;
  int dblk = bid & 7, cb_ = bid >> 3, b = cb_ & 1, c = cb_ >> 1;
  int d = dblk * 256 + tid;
  float Av[16];
  {
    const float4* Ap = (const float4*)(A_log + (long)d * DS);
#pragma unroll
    for (int q = 0; q < 4; ++q) {
      float4 a = Ap[q];
      Av[4*q+0] = -__expf(a.x); Av[4*q+1] = -__expf(a.y);
      Av[4*q+2] = -__expf(a.z); Av[4*q+3] = -__expf(a.w);
    }
  }
  float Dval = Dskip[d];
  float h[16];
  {
    const float4* hp = (const float4*)(h0 + (((long)c * BN + b) * DI + d) * DS);
#pragma unroll
    for (int q = 0; q < 4; ++q) {
      float4 hv = hp[q];
      h[4*q] = hv.x; h[4*q+1] = hv.y; h[4*q+2] = hv.z; h[4*q+3] = hv.w;
    }
  }
  long row = (long)b * TN + c * CL;
  for (int t = 0; t < CL; ++t) {
    long rw = row + t;
    float dtv = dt[rw * DI + d];
    float uv  = u [rw * DI + d];
    float du = dtv * uv;
    const float4* Bp = (const float4*)(xdbl + rw * XDP + RK);
    const float4* Cp = (const float4*)(xdbl + rw * XDP + RK + DS);
    float y = 0.f;
#pragma unroll
    for (int q = 0; q < 4; ++q) {
      float4 Bv = Bp[q];
      float4 Cv = Cp[q];
      h[4*q+0] = fmaf(fexp(dtv * Av[4*q+0]), h[4*q+0], du * Bv.x);
      h[4*q+1] = fmaf(fexp(dtv * Av[4*q+1]), h[4*q+1], du * Bv.y);
      h[4*q+2] = fmaf(fexp(dtv * Av[4*q+2]), h[4*q+2], du * Bv.z);
      h[4*q+3] = fmaf(fexp(dtv * Av[4*q+3]), h[4*q+3], du * Bv.w);
      y = fmaf(h[4*q+0], Cv.x, y);
      y = fmaf(h[4*q+1], Cv.y, y);
      y = fmaf(h[4*q+2], Cv.z, y);
      y = fmaf(h[4*q+3], Cv.w, y);
    }
    float zv = b2f(xz[rw * (2 * DI) + DI + d]);
    ybf[rw * DI + d] = f2b((y + uv * Dval) * fsilu(zv));
  }
}

// out = LN(h)*w + b + resid ; optional bf16 copy of out
__global__ __launch_bounds__(256) void ln_res(const float* __restrict__ h,
    const float* __restrict__ resid, const float* __restrict__ w,
    const float* __restrict__ bb, float* __restrict__ out, short* __restrict__ ob) {
  int row = blockIdx.x;
  int tid = threadIdx.x;
  const float4* hr = (const float4*)(h + (long)row * DM);
  float4 v = hr[tid];
  __shared__ float sm[256];
  float s = v.x + v.y + v.z + v.w;
  sm[tid] = s; __syncthreads();
  for (int st = 128; st > 0; st >>= 1) { if (tid < st) sm[tid] += sm[tid + st]; __syncthreads(); }
  float mean = sm[0] * (1.f / DM);
  __syncthreads();
  float4 c;
  c.x = v.x - mean; c.y = v.y - mean; c.z = v.z - mean; c.w = v.w - mean;
  float s2 = c.x * c.x + c.y * c.y + c.z * c.z + c.w * c.w;
  sm[tid] = s2; __syncthreads();
  for (int st = 128; st > 0; st >>= 1) { if (tid < st) sm[tid] += sm[tid + st]; __syncthreads(); }
  float inv = rsqrtf(sm[0] * (1.f / DM) + 1e-5f);
  const float4 rv = ((const float4*)(resid + (long)row * DM))[tid];
  const float4 wv = ((const float4*)w)[tid];
  const float4 bv = ((const float4*)bb)[tid];
  float4 ov;
  ov.x = c.x * inv * wv.x + bv.x + rv.x;
  ov.y = c.y * inv * wv.y + bv.y + rv.y;
  ov.z = c.z * inv * wv.z + bv.z + rv.z;
  ov.w = c.w * inv * wv.w + bv.w + rv.w;
  ((float4*)(out + (long)row * DM))[tid] = ov;
  if (ob) {
    short4 sv; sv.x = f2b(ov.x); sv.y = f2b(ov.y); sv.z = f2b(ov.z); sv.w = f2b(ov.w);
    *(short4*)(ob + (long)row * DM + tid * 4) = sv;
  }
}

extern "C" void kernel_launch(void* const* d_in, const int* in_sizes, int n_in,
                              void* d_out, int out_size, void* d_ws, size_t ws_size,
                              hipStream_t stream) {
  const float* x     = (const float*)d_in[0];
  const float* inw   = (const float*)d_in[1];
  const float* convw = (const float*)d_in[2];
  const float* convb = (const float*)d_in[3];
  const float* xpw   = (const float*)d_in[4];
  const float* dtw   = (const float*)d_in[5];
  const float* dtbi  = (const float*)d_in[6];
  const float* alog  = (const float*)d_in[7];
  const float* dsk   = (const float*)d_in[8];
  const float* outw  = (const float*)d_in[9];
  const float* lnw   = (const float*)d_in[10];
  const float* lnb   = (const float*)d_in[11];
  float* outp = (float*)d_out;

  char* w = (char*)d_ws; size_t off = 0;
  auto alloc = [&](size_t bytes) { void* p = w + off; off += (bytes + 255) & ~255ULL; return p; };
  short* inw_bf  = (short*)alloc((size_t)2 * 2 * DI * DM * 2);  // both layers
  short* outw_bf = (short*)alloc((size_t)2 * DM * DI * 2);
  short* dtw_bf  = (short*)alloc((size_t)2 * DI * RK * 2);
  short* xpw_bf  = (short*)alloc((size_t)2 * XDP * DI * 2);     // padded
  short* abuf    = (short*)alloc((size_t)MROWS * DI * 2);       // xbf / ybf
  short* xzbf    = (short*)alloc((size_t)MROWS * 2 * DI * 2);
  float* ub      = (float*)alloc((size_t)MROWS * DI * 4);
  short* ubf     = (short*)alloc((size_t)MROWS * DI * 2);
  float* xpart   = (float*)alloc((size_t)XPZ * MROWS * XDP * 4);
  float* xdb     = (float*)alloc((size_t)MROWS * XDP * 4);
  short* xdbf    = (short*)alloc((size_t)MROWS * XDP * 2);
  float* dtb     = (float*)alloc((size_t)MROWS * DI * 4);
  float* hloc    = (float*)alloc((size_t)NC * BN * DI * DS * 4);
  float* prodb   = (float*)alloc((size_t)NC * BN * DI * DS * 4);
  float* h0      = (float*)alloc((size_t)NC * BN * DI * DS * 4);
  float* hb      = (float*)alloc((size_t)MROWS * DM * 4);
  float* xcur    = (float*)alloc((size_t)MROWS * DM * 4);

  // one-shot conversions (both layers)
  f2bf_k<<<(MROWS * DM / 4 + 255) / 256, 256, 0, stream>>>(x, abuf, MROWS * DM / 4);
  f2bf_k<<<(2 * 2 * DI * DM / 4 + 255) / 256, 256, 0, stream>>>(inw, inw_bf, 2 * 2 * DI * DM / 4);
  f2bf_k<<<(2 * DM * DI / 4 + 255) / 256, 256, 0, stream>>>(outw, outw_bf, 2 * DM * DI / 4);
  f2bf_k<<<(2 * DI * RK / 4 + 255) / 256, 256, 0, stream>>>(dtw, dtw_bf, 2 * DI * RK / 4);
  xpw_pad_k<<<(2 * XDP * DI / 4 + 255) / 256, 256, 0, stream>>>(xpw, xpw_bf);

  const float* lin = x;
  for (int l = 0; l < 2; ++l) {
    // in_proj: [2048,1024] x [4096,1024]^T -> bf16 xz
    gemm_mfma<1, 0><<<dim3((2 * DI) / 128, MROWS / 128), 256, 0, stream>>>(
        abuf, inw_bf + (size_t)l * 2 * DI * DM, nullptr, xzbf,
        MROWS, 2 * DI, DM, DM, DM, 2 * DI, nullptr, 0);

    conv_silu<<<(MROWS * DI) / 256, 256, 0, stream>>>(
        xzbf, convw + (size_t)l * DI * 4, convb + (size_t)l * DI, ub, ubf);

    // x_proj: MFMA split-K=8 -> partials, then reduce
    gemm_mfma<0, 1><<<dim3(1, MROWS / 128, XPZ), 256, 0, stream>>>(
        ubf, xpw_bf + (size_t)l * XDP * DI, xpart, nullptr,
        MROWS, XDP, DI, DI, DI, XDP, nullptr, DI / XPZ);
    reduce_xp<<<(MROWS * XDP) / 256, 256, 0, stream>>>(xpart, xdb, xdbf);

    // dt_proj + softplus (MFMA, K=64)
    gemm_mfma<2, 0><<<dim3(DI / 128, MROWS / 128), 256, 0, stream>>>(
        xdbf, dtw_bf + (size_t)l * DI * RK, dtb, nullptr,
        MROWS, DI, RK, XDP, RK, DI, dtbi + (size_t)l * DI, 0);

    // chunked scan (channel-per-thread)
    scan_p1<<<NC * BN * (DI / 256), 256, 0, stream>>>(dtb, ub, xdb,
        alog + (size_t)l * DI * DS, hloc, prodb);
    scan_p2<<<(BN * DI * DS) / 256, 256, 0, stream>>>(hloc, prodb, h0);
    scan_p3<<<NC * BN * (DI / 256), 256, 0, stream>>>(dtb, ub, xdb, xzbf,
        alog + (size_t)l * DI * DS, dsk + (size_t)l * DI, h0, abuf);

    // out_proj: [2048,2048] x [1024,2048]^T -> fp32 hb
    gemm_mfma<0, 0><<<dim3(DM / 128, MROWS / 128), 256, 0, stream>>>(
        abuf, outw_bf + (size_t)l * DM * DI, hb, nullptr,
        MROWS, DM, DI, DI, DI, DM, nullptr, 0);

    float* lo = (l == 0) ? xcur : outp;
    short* lob = (l == 0) ? abuf : nullptr;
    ln_res<<<MROWS, 256, 0, stream>>>(hb, lin,
        lnw + (size_t)l * DM, lnb + (size_t)l * DM, lo, lob);
    lin = xcur;
  }
}

// Round 6
// 321.929 us; speedup vs baseline: 11.5658x; 1.1660x over previous
//
#include <hip/hip_runtime.h>

constexpr int BN = 2;       // batch
constexpr int TN = 1024;    // seq len
constexpr int DM = 1024;    // d_model
constexpr int DI = 2048;    // d_inner
constexpr int DS = 16;      // d_state
constexpr int RK = 64;      // dt_rank
constexpr int XD = 96;      // dt_rank + 2*d_state
constexpr int XDP = 128;    // padded x_dbl stride
constexpr int MROWS = BN * TN; // 2048
constexpr int NC = 32;      // scan chunks
constexpr int CL = 32;      // chunk length (NC*CL == TN)
constexpr int XPZ = 8;      // x_proj split-K factor
constexpr int OPZ = 4;      // out_proj split-K factor

using f32x4  = __attribute__((ext_vector_type(4))) float;
using bf16x8 = __attribute__((ext_vector_type(8))) short;

__device__ inline short f2b(float f) {
  union { float f; unsigned u; } v; v.f = f;
  unsigned r = (v.u + 0x7FFFu + ((v.u >> 16) & 1u)) >> 16;
  return (short)r;
}
__device__ inline float b2f(short s) {
  union { unsigned u; float f; } v; v.u = ((unsigned)(unsigned short)s) << 16;
  return v.f;
}
// native-instruction transcendentals (v_exp_f32 / v_rcp_f32)
__device__ inline float fexp(float x) { return __builtin_amdgcn_exp2f(x * 1.4426950408889634f); }
__device__ inline float fsilu(float x) { return x * __builtin_amdgcn_rcpf(1.f + fexp(-x)); }
__device__ inline float fsoftplus(float v) { return (v > 15.f) ? v : __logf(1.f + __expf(v)); }

__device__ inline void gl_lds16(const void* g, void* l) {
  __builtin_amdgcn_global_load_lds((const __attribute__((address_space(1))) void*)g,
                                   (__attribute__((address_space(3))) void*)l, 16, 0, 0);
}

// fp32 -> bf16 convert, 4 elems/thread
__global__ __launch_bounds__(256) void f2bf_k(const float* __restrict__ in,
    short* __restrict__ out, int n4) {
  int i = blockIdx.x * 256 + threadIdx.x;
  if (i >= n4) return;
  float4 v = ((const float4*)in)[i];
  short4 s; s.x = f2b(v.x); s.y = f2b(v.y); s.z = f2b(v.z); s.w = f2b(v.w);
  ((short4*)out)[i] = s;
}

// x_proj weight [L][XD][DI] fp32 -> padded [L][XDP][DI] bf16 (rows >= XD zero)
__global__ __launch_bounds__(256) void xpw_pad_k(const float* __restrict__ in,
    short* __restrict__ out) {
  int i = blockIdx.x * 256 + threadIdx.x;        // over 2*XDP*DI/4
  int c4 = i & (DI / 4 - 1);
  int rl = i >> 9;                                // row + layer*XDP
  int r = rl & (XDP - 1), l = rl >> 7;
  short4 s;
  if (r < XD) {
    float4 v = ((const float4*)(in + ((long)l * XD + r) * DI))[c4];
    s.x = f2b(v.x); s.y = f2b(v.y); s.z = f2b(v.z); s.w = f2b(v.w);
  } else { s.x = s.y = s.z = s.w = 0; }
  ((short4*)(out + ((long)l * XDP + r) * DI))[c4] = s;
}

// ---------------- bf16 MFMA GEMM: C = A[M,K](lda) * Bw[N,K](ldb)^T --------
// tile 128x128, BK=32, 4 waves (2x2), each wave 64x64 = 4x4 frags of 16x16x32.
// Double-buffered LDS + prefetch: stage(next) issued before compute(cur),
// counted s_waitcnt vmcnt(4), raw barriers (T3-minimum 2-phase recipe).
// MODE 0: fp32 out; MODE 1: bf16 out; MODE 2: fp32 softplus(acc+bias[n])
// KS 1: split-K over blockIdx.z (ksplit per z), partial out at z*M*ldc
template<int MODE, int KS>
__global__ __launch_bounds__(256) void gemm_mfma(const short* __restrict__ A,
    const short* __restrict__ Bw, float* __restrict__ Cf, short* __restrict__ Cb,
    int M, int N, int K, int lda, int ldb, int ldc,
    const float* __restrict__ bias, int ksplit) {
  __shared__ alignas(16) short As[2][128 * 32];
  __shared__ alignas(16) short Bs[2][128 * 32];
  const int tid = threadIdx.x;
  const int wid = tid >> 6, lane = tid & 63;
  const int row0 = blockIdx.y * 128, col0 = blockIdx.x * 128;
  const int wr = (wid >> 1) * 64, wc = (wid & 1) * 64;
  const int srow = tid >> 2;          // staging row within 64-row round
  const int scol = (tid & 3) * 8;     // staging col (8 bf16 = 16B)
  f32x4 acc[4][4] = {};
  const int kbeg = KS ? blockIdx.z * ksplit : 0;
  const int kend = KS ? kbeg + ksplit : K;

  auto stage = [&](int buf, int k0) {
#pragma unroll
    for (int r = 0; r < 2; ++r) {
      gl_lds16(A  + (long)(row0 + r * 64 + srow) * lda + k0 + scol,
               (short*)((char*)As[buf] + r * 4096 + wid * 1024));
      gl_lds16(Bw + (long)(col0 + r * 64 + srow) * ldb + k0 + scol,
               (short*)((char*)Bs[buf] + r * 4096 + wid * 1024));
    }
  };

  stage(0, kbeg);
  int buf = 0;
  for (int k0 = kbeg; k0 < kend; k0 += 32, buf ^= 1) {
    if (k0 + 32 < kend) {
      stage(buf ^ 1, k0 + 32);                       // prefetch next tile
      asm volatile("s_waitcnt vmcnt(4)" ::: "memory"); // cur tile landed
    } else {
      asm volatile("s_waitcnt vmcnt(0)" ::: "memory");
    }
    __builtin_amdgcn_s_barrier();
    bf16x8 af[4], bv[4];
#pragma unroll
    for (int i = 0; i < 4; ++i)
      af[i] = *(const bf16x8*)(As[buf] + (wr + i * 16 + (lane & 15)) * 32 + (lane >> 4) * 8);
#pragma unroll
    for (int j = 0; j < 4; ++j)
      bv[j] = *(const bf16x8*)(Bs[buf] + (wc + j * 16 + (lane & 15)) * 32 + (lane >> 4) * 8);
#pragma unroll
    for (int i = 0; i < 4; ++i)
#pragma unroll
      for (int j = 0; j < 4; ++j)
        acc[i][j] = __builtin_amdgcn_mfma_f32_16x16x32_bf16(af[i], bv[j], acc[i][j], 0, 0, 0);
    __builtin_amdgcn_s_barrier();   // all waves done reading buf before re-stage
  }
  const long zbase = KS ? (long)blockIdx.z * M * ldc : 0;
#pragma unroll
  for (int i = 0; i < 4; ++i) {
#pragma unroll
    for (int j = 0; j < 4; ++j) {
      int gcol = col0 + wc + j * 16 + (lane & 15);
#pragma unroll
      for (int r = 0; r < 4; ++r) {
        int grow = row0 + wr + i * 16 + (lane >> 4) * 4 + r;
        if (MODE == 1) Cb[(long)grow * ldc + gcol] = f2b(acc[i][j][r]);
        else if (MODE == 2) {
          float v = acc[i][j][r] + bias[gcol];
          Cf[(long)grow * ldc + gcol] = fsoftplus(v);
        } else Cf[zbase + (long)grow * ldc + gcol] = acc[i][j][r];
      }
    }
  }
}

// sum XPZ split-K partials of x_proj; emit fp32 (stride XDP) + bf16
__global__ __launch_bounds__(256) void reduce_xp(const float* __restrict__ part,
    float* __restrict__ out, short* __restrict__ outb) {
  int i = blockIdx.x * 256 + threadIdx.x;   // over MROWS*XDP
  const int n = MROWS * XDP;
  float s = 0.f;
#pragma unroll
  for (int z = 0; z < XPZ; ++z) s += part[(long)z * n + i];
  out[i] = s;
  outb[i] = f2b(s);
}

// u = silu(causal depthwise conv(xc) + cb); bf16 out only
__global__ __launch_bounds__(256) void conv_silu(const short* __restrict__ xz,
    const float* __restrict__ cw, const float* __restrict__ cb,
    short* __restrict__ ubf) {
  int idx = blockIdx.x * 256 + threadIdx.x;  // MROWS*DI
  int d = idx & (DI - 1);
  int bt = idx >> 11;
  int t = bt & (TN - 1);
  long rowb = (long)(bt - t);
  float acc = cb[d];
#pragma unroll
  for (int k = 0; k < 4; ++k) {
    int ts = t - 3 + k;
    if (ts >= 0) acc = fmaf(b2f(xz[(rowb + ts) * (2 * DI) + d]), cw[d * 4 + k], acc);
  }
  ubf[idx] = f2b(fsilu(acc));
}

// ---------------- chunked selective scan (channel-per-thread) ----------------
// phase 1: local scan (h0=0) -> hloc, decay product -> prodb
__global__ __launch_bounds__(256) void scan_p1(const float* __restrict__ dt,
    const short* __restrict__ u, const float* __restrict__ xdbl,
    const float* __restrict__ A_log, float* __restrict__ hloc,
    float* __restrict__ prodb) {
  int tid = threadIdx.x;
  int bid = blockIdx.x;              // ((c*BN + b)*8 + dblk)
  int dblk = bid & 7, cb_ = bid >> 3, b = cb_ & 1, c = cb_ >> 1;
  int d = dblk * 256 + tid;
  float Av[16];
  {
    const float4* Ap = (const float4*)(A_log + (long)d * DS);
#pragma unroll
    for (int q = 0; q < 4; ++q) {
      float4 a = Ap[q];
      Av[4*q+0] = -__expf(a.x); Av[4*q+1] = -__expf(a.y);
      Av[4*q+2] = -__expf(a.z); Av[4*q+3] = -__expf(a.w);
    }
  }
  float h[16] = {};
  float sdt = 0.f;
  long row = (long)b * TN + c * CL;
  for (int t = 0; t < CL; ++t) {
    long rw = row + t;
    float dtv = dt[rw * DI + d];
    float uv  = b2f(u[rw * DI + d]);
    float du = dtv * uv;
    sdt += dtv;
    const float4* Bp = (const float4*)(xdbl + rw * XDP + RK);
#pragma unroll
    for (int q = 0; q < 4; ++q) {
      float4 Bv = Bp[q];
      h[4*q+0] = fmaf(fexp(dtv * Av[4*q+0]), h[4*q+0], du * Bv.x);
      h[4*q+1] = fmaf(fexp(dtv * Av[4*q+1]), h[4*q+1], du * Bv.y);
      h[4*q+2] = fmaf(fexp(dtv * Av[4*q+2]), h[4*q+2], du * Bv.z);
      h[4*q+3] = fmaf(fexp(dtv * Av[4*q+3]), h[4*q+3], du * Bv.w);
    }
  }
  long o = (((long)c * BN + b) * DI + d) * DS;
  float4* hp = (float4*)(hloc + o);
  float4* pp = (float4*)(prodb + o);
#pragma unroll
  for (int q = 0; q < 4; ++q) {
    float4 hv; hv.x = h[4*q]; hv.y = h[4*q+1]; hv.z = h[4*q+2]; hv.w = h[4*q+3];
    hp[q] = hv;
    float4 pv;
    pv.x = fexp(sdt * Av[4*q+0]); pv.y = fexp(sdt * Av[4*q+1]);
    pv.z = fexp(sdt * Av[4*q+2]); pv.w = fexp(sdt * Av[4*q+3]);
    pp[q] = pv;
  }
}

// phase 2: sequential combine over chunks (per state)
__global__ __launch_bounds__(256) void scan_p2(const float* __restrict__ hloc,
    const float* __restrict__ prodb, float* __restrict__ h0) {
  long idx = blockIdx.x * 256 + threadIdx.x;  // BN*DI*DS = 65536
  float carry = 0.f;
  for (int c = 0; c < NC; ++c) {
    long o = (long)c * (BN * DI * DS) + idx;
    h0[o] = carry;
    carry = fmaf(prodb[o], carry, hloc[o]);
  }
}

// phase 3: replay chunk from carried state; y = (h.C + u*D)*silu(z) -> bf16
__global__ __launch_bounds__(256) void scan_p3(const float* __restrict__ dt,
    const short* __restrict__ u, const float* __restrict__ xdbl,
    const short* __restrict__ xz, const float* __restrict__ A_log,
    const float* __restrict__ Dskip, const float* __restrict__ h0,
    short* __restrict__ ybf) {
  int tid = threadIdx.x;
  int bid = blockIdx.x;
  int dblk = bid & 7, cb_ = bid >> 3, b = cb_ & 1, c = cb_ >> 1;
  int d = dblk * 256 + tid;
  float Av[16];
  {
    const float4* Ap = (const float4*)(A_log + (long)d * DS);
#pragma unroll
    for (int q = 0; q < 4; ++q) {
      float4 a = Ap[q];
      Av[4*q+0] = -__expf(a.x); Av[4*q+1] = -__expf(a.y);
      Av[4*q+2] = -__expf(a.z); Av[4*q+3] = -__expf(a.w);
    }
  }
  float Dval = Dskip[d];
  float h[16];
  {
    const float4* hp = (const float4*)(h0 + (((long)c * BN + b) * DI + d) * DS);
#pragma unroll
    for (int q = 0; q < 4; ++q) {
      float4 hv = hp[q];
      h[4*q] = hv.x; h[4*q+1] = hv.y; h[4*q+2] = hv.z; h[4*q+3] = hv.w;
    }
  }
  long row = (long)b * TN + c * CL;
  for (int t = 0; t < CL; ++t) {
    long rw = row + t;
    float dtv = dt[rw * DI + d];
    float uv  = b2f(u[rw * DI + d]);
    float du = dtv * uv;
    const float4* Bp = (const float4*)(xdbl + rw * XDP + RK);
    const float4* Cp = (const float4*)(xdbl + rw * XDP + RK + DS);
    float y = 0.f;
#pragma unroll
    for (int q = 0; q < 4; ++q) {
      float4 Bv = Bp[q];
      float4 Cv = Cp[q];
      h[4*q+0] = fmaf(fexp(dtv * Av[4*q+0]), h[4*q+0], du * Bv.x);
      h[4*q+1] = fmaf(fexp(dtv * Av[4*q+1]), h[4*q+1], du * Bv.y);
      h[4*q+2] = fmaf(fexp(dtv * Av[4*q+2]), h[4*q+2], du * Bv.z);
      h[4*q+3] = fmaf(fexp(dtv * Av[4*q+3]), h[4*q+3], du * Bv.w);
      y = fmaf(h[4*q+0], Cv.x, y);
      y = fmaf(h[4*q+1], Cv.y, y);
      y = fmaf(h[4*q+2], Cv.z, y);
      y = fmaf(h[4*q+3], Cv.w, y);
    }
    float zv = b2f(xz[rw * (2 * DI) + DI + d]);
    ybf[rw * DI + d] = f2b((y + uv * Dval) * fsilu(zv));
  }
}

// out = LN(sum_z hp[z])*w + b + resid ; optional bf16 copy of out
__global__ __launch_bounds__(256) void ln_res(const float* __restrict__ hp,
    const float* __restrict__ resid, const float* __restrict__ w,
    const float* __restrict__ bb, float* __restrict__ out, short* __restrict__ ob) {
  int row = blockIdx.x;
  int tid = threadIdx.x;
  const long n = (long)MROWS * DM;
  const long base = (long)row * DM;
  float4 v;
  {
    float4 p0 = ((const float4*)(hp + base))[tid];
    float4 p1 = ((const float4*)(hp + n + base))[tid];
    float4 p2 = ((const float4*)(hp + 2 * n + base))[tid];
    float4 p3 = ((const float4*)(hp + 3 * n + base))[tid];
    v.x = p0.x + p1.x + p2.x + p3.x;
    v.y = p0.y + p1.y + p2.y + p3.y;
    v.z = p0.z + p1.z + p2.z + p3.z;
    v.w = p0.w + p1.w + p2.w + p3.w;
  }
  __shared__ float sm[256];
  float s = v.x + v.y + v.z + v.w;
  sm[tid] = s; __syncthreads();
  for (int st = 128; st > 0; st >>= 1) { if (tid < st) sm[tid] += sm[tid + st]; __syncthreads(); }
  float mean = sm[0] * (1.f / DM);
  __syncthreads();
  float4 c;
  c.x = v.x - mean; c.y = v.y - mean; c.z = v.z - mean; c.w = v.w - mean;
  float s2 = c.x * c.x + c.y * c.y + c.z * c.z + c.w * c.w;
  sm[tid] = s2; __syncthreads();
  for (int st = 128; st > 0; st >>= 1) { if (tid < st) sm[tid] += sm[tid + st]; __syncthreads(); }
  float inv = rsqrtf(sm[0] * (1.f / DM) + 1e-5f);
  const float4 rv = ((const float4*)(resid + base))[tid];
  const float4 wv = ((const float4*)w)[tid];
  const float4 bv = ((const float4*)bb)[tid];
  float4 ov;
  ov.x = c.x * inv * wv.x + bv.x + rv.x;
  ov.y = c.y * inv * wv.y + bv.y + rv.y;
  ov.z = c.z * inv * wv.z + bv.z + rv.z;
  ov.w = c.w * inv * wv.w + bv.w + rv.w;
  ((float4*)(out + base))[tid] = ov;
  if (ob) {
    short4 sv; sv.x = f2b(ov.x); sv.y = f2b(ov.y); sv.z = f2b(ov.z); sv.w = f2b(ov.w);
    *(short4*)(ob + base + tid * 4) = sv;
  }
}

extern "C" void kernel_launch(void* const* d_in, const int* in_sizes, int n_in,
                              void* d_out, int out_size, void* d_ws, size_t ws_size,
                              hipStream_t stream) {
  const float* x     = (const float*)d_in[0];
  const float* inw   = (const float*)d_in[1];
  const float* convw = (const float*)d_in[2];
  const float* convb = (const float*)d_in[3];
  const float* xpw   = (const float*)d_in[4];
  const float* dtw   = (const float*)d_in[5];
  const float* dtbi  = (const float*)d_in[6];
  const float* alog  = (const float*)d_in[7];
  const float* dsk   = (const float*)d_in[8];
  const float* outw  = (const float*)d_in[9];
  const float* lnw   = (const float*)d_in[10];
  const float* lnb   = (const float*)d_in[11];
  float* outp = (float*)d_out;

  char* w = (char*)d_ws; size_t off = 0;
  auto alloc = [&](size_t bytes) { void* p = w + off; off += (bytes + 255) & ~255ULL; return p; };
  short* inw_bf  = (short*)alloc((size_t)2 * 2 * DI * DM * 2);  // both layers
  short* outw_bf = (short*)alloc((size_t)2 * DM * DI * 2);
  short* dtw_bf  = (short*)alloc((size_t)2 * DI * RK * 2);
  short* xpw_bf  = (short*)alloc((size_t)2 * XDP * DI * 2);     // padded
  short* abuf    = (short*)alloc((size_t)MROWS * DI * 2);       // xbf / ybf
  short* xzbf    = (short*)alloc((size_t)MROWS * 2 * DI * 2);
  short* ubf     = (short*)alloc((size_t)MROWS * DI * 2);
  // time-shared scratch arena: xpart (8MB) -> scan temps (25MB) -> hb4 (33.6MB)
  float* arena   = (float*)alloc((size_t)OPZ * MROWS * DM * 4);
  float* xpart   = arena;
  float* hloc    = arena;
  float* prodb   = arena +     (size_t)NC * BN * DI * DS;
  float* h0      = arena + 2 * (size_t)NC * BN * DI * DS;
  float* hb4     = arena;
  float* xdb     = (float*)alloc((size_t)MROWS * XDP * 4);
  short* xdbf    = (short*)alloc((size_t)MROWS * XDP * 2);
  float* dtb     = (float*)alloc((size_t)MROWS * DI * 4);
  float* xcur    = (float*)alloc((size_t)MROWS * DM * 4);

  // one-shot conversions (both layers)
  f2bf_k<<<(MROWS * DM / 4 + 255) / 256, 256, 0, stream>>>(x, abuf, MROWS * DM / 4);
  f2bf_k<<<(2 * 2 * DI * DM / 4 + 255) / 256, 256, 0, stream>>>(inw, inw_bf, 2 * 2 * DI * DM / 4);
  f2bf_k<<<(2 * DM * DI / 4 + 255) / 256, 256, 0, stream>>>(outw, outw_bf, 2 * DM * DI / 4);
  f2bf_k<<<(2 * DI * RK / 4 + 255) / 256, 256, 0, stream>>>(dtw, dtw_bf, 2 * DI * RK / 4);
  xpw_pad_k<<<(2 * XDP * DI / 4 + 255) / 256, 256, 0, stream>>>(xpw, xpw_bf);

  const float* lin = x;
  for (int l = 0; l < 2; ++l) {
    // in_proj: [2048,1024] x [4096,1024]^T -> bf16 xz
    gemm_mfma<1, 0><<<dim3((2 * DI) / 128, MROWS / 128), 256, 0, stream>>>(
        abuf, inw_bf + (size_t)l * 2 * DI * DM, nullptr, xzbf,
        MROWS, 2 * DI, DM, DM, DM, 2 * DI, nullptr, 0);

    conv_silu<<<(MROWS * DI) / 256, 256, 0, stream>>>(
        xzbf, convw + (size_t)l * DI * 4, convb + (size_t)l * DI, ubf);

    // x_proj: MFMA split-K=8 -> partials, then reduce
    gemm_mfma<0, 1><<<dim3(1, MROWS / 128, XPZ), 256, 0, stream>>>(
        ubf, xpw_bf + (size_t)l * XDP * DI, xpart, nullptr,
        MROWS, XDP, DI, DI, DI, XDP, nullptr, DI / XPZ);
    reduce_xp<<<(MROWS * XDP) / 256, 256, 0, stream>>>(xpart, xdb, xdbf);

    // dt_proj + softplus (MFMA, K=64)
    gemm_mfma<2, 0><<<dim3(DI / 128, MROWS / 128), 256, 0, stream>>>(
        xdbf, dtw_bf + (size_t)l * DI * RK, dtb, nullptr,
        MROWS, DI, RK, XDP, RK, DI, dtbi + (size_t)l * DI, 0);

    // chunked scan (channel-per-thread)
    scan_p1<<<NC * BN * (DI / 256), 256, 0, stream>>>(dtb, ubf, xdb,
        alog + (size_t)l * DI * DS, hloc, prodb);
    scan_p2<<<(BN * DI * DS) / 256, 256, 0, stream>>>(hloc, prodb, h0);
    scan_p3<<<NC * BN * (DI / 256), 256, 0, stream>>>(dtb, ubf, xdb, xzbf,
        alog + (size_t)l * DI * DS, dsk + (size_t)l * DI, h0, abuf);

    // out_proj: split-K=4 -> 4 fp32 partials (reduced inside ln_res)
    gemm_mfma<0, 1><<<dim3(DM / 128, MROWS / 128, OPZ), 256, 0, stream>>>(
        abuf, outw_bf + (size_t)l * DM * DI, hb4, nullptr,
        MROWS, DM, DI, DI, DI, DM, nullptr, DI / OPZ);

    float* lo = (l == 0) ? xcur : outp;
    short* lob = (l == 0) ? abuf : nullptr;
    ln_res<<<MROWS, 256, 0, stream>>>(hb4, lin,
        lnw + (size_t)l * DM, lnb + (size_t)l * DM, lo, lob);
    lin = xcur;
  }
}

// Round 8
// 297.887 us; speedup vs baseline: 12.4992x; 1.0807x over previous
//
#include <hip/hip_runtime.h>

constexpr int BN = 2;       // batch
constexpr int TN = 1024;    // seq len
constexpr int DM = 1024;    // d_model
constexpr int DI = 2048;    // d_inner
constexpr int DS = 16;      // d_state
constexpr int RK = 64;      // dt_rank
constexpr int XD = 96;      // dt_rank + 2*d_state
constexpr int XDP = 128;    // padded x_dbl stride
constexpr int MROWS = BN * TN; // 2048
constexpr int NC = 32;      // scan chunks
constexpr int CL = 32;      // chunk length (NC*CL == TN)
constexpr int XPZ = 8;      // x_proj split-K factor
constexpr int OPZ = 4;      // out_proj split-K factor

using f32x4  = __attribute__((ext_vector_type(4))) float;
using bf16x8 = __attribute__((ext_vector_type(8))) short;

__device__ inline short f2b(float f) {
  union { float f; unsigned u; } v; v.f = f;
  unsigned r = (v.u + 0x7FFFu + ((v.u >> 16) & 1u)) >> 16;
  return (short)r;
}
__device__ inline float b2f(short s) {
  union { unsigned u; float f; } v; v.u = ((unsigned)(unsigned short)s) << 16;
  return v.f;
}
// native-instruction transcendentals (v_exp_f32 / v_rcp_f32)
__device__ inline float fexp(float x) { return __builtin_amdgcn_exp2f(x * 1.4426950408889634f); }
__device__ inline float fsilu(float x) { return x * __builtin_amdgcn_rcpf(1.f + fexp(-x)); }
__device__ inline float fsoftplus(float v) { return (v > 15.f) ? v : __logf(1.f + __expf(v)); }

__device__ inline void gl_lds16(const void* g, void* l) {
  __builtin_amdgcn_global_load_lds((const __attribute__((address_space(1))) void*)g,
                                   (__attribute__((address_space(3))) void*)l, 16, 0, 0);
}

// ---------- fused preamble: all fp32->bf16 conversions in one launch ----------
constexpr int PR0 = MROWS * DM / 4;
constexpr int PR1 = PR0 + 4 * DI * DM / 4;
constexpr int PR2 = PR1 + 2 * DM * DI / 4;
constexpr int PR3 = PR2 + 2 * DI * RK / 4;
constexpr int PR4 = PR3 + 2 * XDP * DI / 4;
__global__ __launch_bounds__(256) void prep_k(const float* __restrict__ x,
    const float* __restrict__ inw, const float* __restrict__ outw,
    const float* __restrict__ dtw, const float* __restrict__ xpw,
    short* __restrict__ abuf, short* __restrict__ inw_bf,
    short* __restrict__ outw_bf, short* __restrict__ dtw_bf,
    short* __restrict__ xpw_bf) {
  int i = blockIdx.x * 256 + threadIdx.x;
  if (i >= PR4) return;
  const float* src = nullptr; short* dst = nullptr; int j = i;
  if (i < PR0)      { src = x;    dst = abuf;    }
  else if (i < PR1) { j = i - PR0; src = inw;  dst = inw_bf;  }
  else if (i < PR2) { j = i - PR1; src = outw; dst = outw_bf; }
  else if (i < PR3) { j = i - PR2; src = dtw;  dst = dtw_bf;  }
  else {
    j = i - PR3;                       // padded xpw region
    int c4 = j & (DI / 4 - 1);
    int rl = j >> 9;
    int r = rl & (XDP - 1), l = rl >> 7;
    short4 s;
    if (r < XD) {
      float4 v = ((const float4*)(xpw + ((long)l * XD + r) * DI))[c4];
      s.x = f2b(v.x); s.y = f2b(v.y); s.z = f2b(v.z); s.w = f2b(v.w);
    } else { s.x = s.y = s.z = s.w = 0; }
    ((short4*)xpw_bf)[j] = s;
    return;
  }
  float4 v = ((const float4*)src)[j];
  short4 s; s.x = f2b(v.x); s.y = f2b(v.y); s.z = f2b(v.z); s.w = f2b(v.w);
  ((short4*)dst)[j] = s;
}

// ---------------- bf16 MFMA GEMM: C = A[M,K](lda) * Bw[N,K](ldb)^T --------
// tile 128x128, BK=64, 4 waves (2x2), wave 64x64 = 4x4 frags of 16x16x32.
// LDS rows are 128B -> G4 XOR swizzle (chunk ^= row&7), applied as
// pre-swizzled GLOBAL source (gl_lds dest stays linear) + swizzled ds_read.
// Row (r2*32+tr) lives at byte (r2*32+tr)*128 = r2*4096 + tid*16 - (tid&7)*16... 
// i.e. dest = r2*4096 + tid*16 (32-row round = 4096 B).   [R7 bug: was r2*8192]
// Double-buffered, counted s_waitcnt vmcnt(8) (T4), raw barriers.
// MODE 0: fp32 out; MODE 1: bf16 out; MODE 2: bf16 softplus(acc+bias[n])
// KS 1: split-K over blockIdx.z (ksplit per z, mult of 64), partials at z*M*ldc
template<int MODE, int KS>
__global__ __launch_bounds__(256) void gemm_mfma(const short* __restrict__ A,
    const short* __restrict__ Bw, float* __restrict__ Cf, short* __restrict__ Cb,
    int M, int N, int K, int lda, int ldb, int ldc,
    const float* __restrict__ bias, int ksplit) {
  __shared__ alignas(16) short As[2][128 * 64];
  __shared__ alignas(16) short Bs[2][128 * 64];
  const int tid = threadIdx.x;
  const int wid = tid >> 6, lane = tid & 63;
  const int row0 = blockIdx.y * 128, col0 = blockIdx.x * 128;
  const int wr = (wid >> 1) * 64, wc = (wid & 1) * 64;
  const int tr = tid >> 3;                    // staging row within 32-row round
  const int tg = (tid & 7) ^ (tr & 7);        // pre-swizzled source chunk
  f32x4 acc[4][4] = {};
  const int kbeg = KS ? blockIdx.z * ksplit : 0;
  const int kend = KS ? kbeg + ksplit : K;

  auto stage = [&](int buf, int k0) {         // 8 gl_lds per thread
#pragma unroll
    for (int r2 = 0; r2 < 4; ++r2) {
      gl_lds16(A  + (long)(row0 + r2 * 32 + tr) * lda + k0 + tg * 8,
               (short*)((char*)As[buf] + r2 * 4096 + tid * 16));
      gl_lds16(Bw + (long)(col0 + r2 * 32 + tr) * ldb + k0 + tg * 8,
               (short*)((char*)Bs[buf] + r2 * 4096 + tid * 16));
    }
  };

  stage(0, kbeg);
  int buf = 0;
  for (int k0 = kbeg; k0 < kend; k0 += 64, buf ^= 1) {
    if (k0 + 64 < kend) {
      stage(buf ^ 1, k0 + 64);                       // prefetch next K-tile
      asm volatile("s_waitcnt vmcnt(8)" ::: "memory"); // cur tile landed
    } else {
      asm volatile("s_waitcnt vmcnt(0)" ::: "memory");
    }
    __builtin_amdgcn_s_barrier();
    bf16x8 af[2][4], bv[2][4];
#pragma unroll
    for (int ks = 0; ks < 2; ++ks) {
#pragma unroll
      for (int i = 0; i < 4; ++i) {
        int ca = ((ks * 4 + (lane >> 4)) ^ (lane & 7)) * 8;   // swizzled read
        af[ks][i] = *(const bf16x8*)(As[buf] + (wr + i * 16 + (lane & 15)) * 64 + ca);
        bv[ks][i] = *(const bf16x8*)(Bs[buf] + (wc + i * 16 + (lane & 15)) * 64 + ca);
      }
    }
#pragma unroll
    for (int ks = 0; ks < 2; ++ks)
#pragma unroll
      for (int i = 0; i < 4; ++i)
#pragma unroll
        for (int j = 0; j < 4; ++j)
          acc[i][j] = __builtin_amdgcn_mfma_f32_16x16x32_bf16(af[ks][i], bv[ks][j], acc[i][j], 0, 0, 0);
    __builtin_amdgcn_s_barrier();   // all waves done reading buf before re-stage
  }
  const long zbase = KS ? (long)blockIdx.z * M * ldc : 0;
#pragma unroll
  for (int i = 0; i < 4; ++i) {
#pragma unroll
    for (int j = 0; j < 4; ++j) {
      int gcol = col0 + wc + j * 16 + (lane & 15);
#pragma unroll
      for (int r = 0; r < 4; ++r) {
        int grow = row0 + wr + i * 16 + (lane >> 4) * 4 + r;
        if (MODE == 1) Cb[(long)grow * ldc + gcol] = f2b(acc[i][j][r]);
        else if (MODE == 2) {
          float v = acc[i][j][r] + bias[gcol];
          Cb[(long)grow * ldc + gcol] = f2b(fsoftplus(v));
        } else Cf[zbase + (long)grow * ldc + gcol] = acc[i][j][r];
      }
    }
  }
}

// sum XPZ split-K partials of x_proj; emit fp32 (stride XDP) + bf16
__global__ __launch_bounds__(256) void reduce_xp(const float* __restrict__ part,
    float* __restrict__ out, short* __restrict__ outb) {
  int i = blockIdx.x * 256 + threadIdx.x;   // over MROWS*XDP
  const int n = MROWS * XDP;
  float s = 0.f;
#pragma unroll
  for (int z = 0; z < XPZ; ++z) s += part[(long)z * n + i];
  out[i] = s;
  outb[i] = f2b(s);
}

// u = silu(causal depthwise conv(xc) + cb); bf16 out only
__global__ __launch_bounds__(256) void conv_silu(const short* __restrict__ xz,
    const float* __restrict__ cw, const float* __restrict__ cb,
    short* __restrict__ ubf) {
  int idx = blockIdx.x * 256 + threadIdx.x;  // MROWS*DI
  int d = idx & (DI - 1);
  int bt = idx >> 11;
  int t = bt & (TN - 1);
  long rowb = (long)(bt - t);
  float acc = cb[d];
#pragma unroll
  for (int k = 0; k < 4; ++k) {
    int ts = t - 3 + k;
    if (ts >= 0) acc = fmaf(b2f(xz[(rowb + ts) * (2 * DI) + d]), cw[d * 4 + k], acc);
  }
  ubf[idx] = f2b(fsilu(acc));
}

// ---------------- chunked selective scan (channel-per-thread) ----------------
// phase 1: local scan (h0=0) -> hloc, decay product -> prodb
__global__ __launch_bounds__(256) void scan_p1(const short* __restrict__ dt,
    const short* __restrict__ u, const float* __restrict__ xdbl,
    const float* __restrict__ A_log, float* __restrict__ hloc,
    float* __restrict__ prodb) {
  int tid = threadIdx.x;
  int bid = blockIdx.x;              // ((c*BN + b)*8 + dblk)
  int dblk = bid & 7, cb_ = bid >> 3, b = cb_ & 1, c = cb_ >> 1;
  int d = dblk * 256 + tid;
  float Av[16];
  {
    const float4* Ap = (const float4*)(A_log + (long)d * DS);
#pragma unroll
    for (int q = 0; q < 4; ++q) {
      float4 a = Ap[q];
      Av[4*q+0] = -__expf(a.x); Av[4*q+1] = -__expf(a.y);
      Av[4*q+2] = -__expf(a.z); Av[4*q+3] = -__expf(a.w);
    }
  }
  float h[16] = {};
  float sdt = 0.f;
  long row = (long)b * TN + c * CL;
  for (int t = 0; t < CL; ++t) {
    long rw = row + t;
    float dtv = b2f(dt[rw * DI + d]);
    float uv  = b2f(u[rw * DI + d]);
    float du = dtv * uv;
    sdt += dtv;
    const float4* Bp = (const float4*)(xdbl + rw * XDP + RK);
#pragma unroll
    for (int q = 0; q < 4; ++q) {
      float4 Bv = Bp[q];
      h[4*q+0] = fmaf(fexp(dtv * Av[4*q+0]), h[4*q+0], du * Bv.x);
      h[4*q+1] = fmaf(fexp(dtv * Av[4*q+1]), h[4*q+1], du * Bv.y);
      h[4*q+2] = fmaf(fexp(dtv * Av[4*q+2]), h[4*q+2], du * Bv.z);
      h[4*q+3] = fmaf(fexp(dtv * Av[4*q+3]), h[4*q+3], du * Bv.w);
    }
  }
  long o = (((long)c * BN + b) * DI + d) * DS;
  float4* hp = (float4*)(hloc + o);
  float4* pp = (float4*)(prodb + o);
#pragma unroll
  for (int q = 0; q < 4; ++q) {
    float4 hv; hv.x = h[4*q]; hv.y = h[4*q+1]; hv.z = h[4*q+2]; hv.w = h[4*q+3];
    hp[q] = hv;
    float4 pv;
    pv.x = fexp(sdt * Av[4*q+0]); pv.y = fexp(sdt * Av[4*q+1]);
    pv.z = fexp(sdt * Av[4*q+2]); pv.w = fexp(sdt * Av[4*q+3]);
    pp[q] = pv;
  }
}

// phase 2: sequential combine over chunks (per state)
__global__ __launch_bounds__(256) void scan_p2(const float* __restrict__ hloc,
    const float* __restrict__ prodb, float* __restrict__ h0) {
  long idx = blockIdx.x * 256 + threadIdx.x;  // BN*DI*DS = 65536
  float carry = 0.f;
  for (int c = 0; c < NC; ++c) {
    long o = (long)c * (BN * DI * DS) + idx;
    h0[o] = carry;
    carry = fmaf(prodb[o], carry, hloc[o]);
  }
}

// phase 3: replay chunk from carried state; y = (h.C + u*D)*silu(z) -> bf16
__global__ __launch_bounds__(256) void scan_p3(const short* __restrict__ dt,
    const short* __restrict__ u, const float* __restrict__ xdbl,
    const short* __restrict__ xz, const float* __restrict__ A_log,
    const float* __restrict__ Dskip, const float* __restrict__ h0,
    short* __restrict__ ybf) {
  int tid = threadIdx.x;
  int bid = blockIdx.x;
  int dblk = bid & 7, cb_ = bid >> 3, b = cb_ & 1, c = cb_ >> 1;
  int d = dblk * 256 + tid;
  float Av[16];
  {
    const float4* Ap = (const float4*)(A_log + (long)d * DS);
#pragma unroll
    for (int q = 0; q < 4; ++q) {
      float4 a = Ap[q];
      Av[4*q+0] = -__expf(a.x); Av[4*q+1] = -__expf(a.y);
      Av[4*q+2] = -__expf(a.z); Av[4*q+3] = -__expf(a.w);
    }
  }
  float Dval = Dskip[d];
  float h[16];
  {
    const float4* hp = (const float4*)(h0 + (((long)c * BN + b) * DI + d) * DS);
#pragma unroll
    for (int q = 0; q < 4; ++q) {
      float4 hv = hp[q];
      h[4*q] = hv.x; h[4*q+1] = hv.y; h[4*q+2] = hv.z; h[4*q+3] = hv.w;
    }
  }
  long row = (long)b * TN + c * CL;
  for (int t = 0; t < CL; ++t) {
    long rw = row + t;
    float dtv = b2f(dt[rw * DI + d]);
    float uv  = b2f(u[rw * DI + d]);
    float du = dtv * uv;
    const float4* Bp = (const float4*)(xdbl + rw * XDP + RK);
    const float4* Cp = (const float4*)(xdbl + rw * XDP + RK + DS);
    float y = 0.f;
#pragma unroll
    for (int q = 0; q < 4; ++q) {
      float4 Bv = Bp[q];
      float4 Cv = Cp[q];
      h[4*q+0] = fmaf(fexp(dtv * Av[4*q+0]), h[4*q+0], du * Bv.x);
      h[4*q+1] = fmaf(fexp(dtv * Av[4*q+1]), h[4*q+1], du * Bv.y);
      h[4*q+2] = fmaf(fexp(dtv * Av[4*q+2]), h[4*q+2], du * Bv.z);
      h[4*q+3] = fmaf(fexp(dtv * Av[4*q+3]), h[4*q+3], du * Bv.w);
      y = fmaf(h[4*q+0], Cv.x, y);
      y = fmaf(h[4*q+1], Cv.y, y);
      y = fmaf(h[4*q+2], Cv.z, y);
      y = fmaf(h[4*q+3], Cv.w, y);
    }
    float zv = b2f(xz[rw * (2 * DI) + DI + d]);
    ybf[rw * DI + d] = f2b((y + uv * Dval) * fsilu(zv));
  }
}

// out = LN(sum_z hp[z])*w + b + resid ; optional bf16 copy of out
__global__ __launch_bounds__(256) void ln_res(const float* __restrict__ hp,
    const float* __restrict__ resid, const float* __restrict__ w,
    const float* __restrict__ bb, float* __restrict__ out, short* __restrict__ ob) {
  int row = blockIdx.x;
  int tid = threadIdx.x;
  const long n = (long)MROWS * DM;
  const long base = (long)row * DM;
  float4 v;
  {
    float4 p0 = ((const float4*)(hp + base))[tid];
    float4 p1 = ((const float4*)(hp + n + base))[tid];
    float4 p2 = ((const float4*)(hp + 2 * n + base))[tid];
    float4 p3 = ((const float4*)(hp + 3 * n + base))[tid];
    v.x = p0.x + p1.x + p2.x + p3.x;
    v.y = p0.y + p1.y + p2.y + p3.y;
    v.z = p0.z + p1.z + p2.z + p3.z;
    v.w = p0.w + p1.w + p2.w + p3.w;
  }
  __shared__ float sm[256];
  float s = v.x + v.y + v.z + v.w;
  sm[tid] = s; __syncthreads();
  for (int st = 128; st > 0; st >>= 1) { if (tid < st) sm[tid] += sm[tid + st]; __syncthreads(); }
  float mean = sm[0] * (1.f / DM);
  __syncthreads();
  float4 c;
  c.x = v.x - mean; c.y = v.y - mean; c.z = v.z - mean; c.w = v.w - mean;
  float s2 = c.x * c.x + c.y * c.y + c.z * c.z + c.w * c.w;
  sm[tid] = s2; __syncthreads();
  for (int st = 128; st > 0; st >>= 1) { if (tid < st) sm[tid] += sm[tid + st]; __syncthreads(); }
  float inv = rsqrtf(sm[0] * (1.f / DM) + 1e-5f);
  const float4 rv = ((const float4*)(resid + base))[tid];
  const float4 wv = ((const float4*)w)[tid];
  const float4 bv = ((const float4*)bb)[tid];
  float4 ov;
  ov.x = c.x * inv * wv.x + bv.x + rv.x;
  ov.y = c.y * inv * wv.y + bv.y + rv.y;
  ov.z = c.z * inv * wv.z + bv.z + rv.z;
  ov.w = c.w * inv * wv.w + bv.w + rv.w;
  ((float4*)(out + base))[tid] = ov;
  if (ob) {
    short4 sv; sv.x = f2b(ov.x); sv.y = f2b(ov.y); sv.z = f2b(ov.z); sv.w = f2b(ov.w);
    *(short4*)(ob + base + tid * 4) = sv;
  }
}

extern "C" void kernel_launch(void* const* d_in, const int* in_sizes, int n_in,
                              void* d_out, int out_size, void* d_ws, size_t ws_size,
                              hipStream_t stream) {
  const float* x     = (const float*)d_in[0];
  const float* inw   = (const float*)d_in[1];
  const float* convw = (const float*)d_in[2];
  const float* convb = (const float*)d_in[3];
  const float* xpw   = (const float*)d_in[4];
  const float* dtw   = (const float*)d_in[5];
  const float* dtbi  = (const float*)d_in[6];
  const float* alog  = (const float*)d_in[7];
  const float* dsk   = (const float*)d_in[8];
  const float* outw  = (const float*)d_in[9];
  const float* lnw   = (const float*)d_in[10];
  const float* lnb   = (const float*)d_in[11];
  float* outp = (float*)d_out;

  char* w = (char*)d_ws; size_t off = 0;
  auto alloc = [&](size_t bytes) { void* p = w + off; off += (bytes + 255) & ~255ULL; return p; };
  short* inw_bf  = (short*)alloc((size_t)2 * 2 * DI * DM * 2);  // both layers
  short* outw_bf = (short*)alloc((size_t)2 * DM * DI * 2);
  short* dtw_bf  = (short*)alloc((size_t)2 * DI * RK * 2);
  short* xpw_bf  = (short*)alloc((size_t)2 * XDP * DI * 2);     // padded
  short* abuf    = (short*)alloc((size_t)MROWS * DI * 2);       // xbf / ybf
  short* xzbf    = (short*)alloc((size_t)MROWS * 2 * DI * 2);
  short* ubf     = (short*)alloc((size_t)MROWS * DI * 2);
  // time-shared scratch arena: xpart (8MB) -> scan temps (25MB) -> hb4 (33.6MB)
  float* arena   = (float*)alloc((size_t)OPZ * MROWS * DM * 4);
  float* xpart   = arena;
  float* hloc    = arena;
  float* prodb   = arena +     (size_t)NC * BN * DI * DS;
  float* h0      = arena + 2 * (size_t)NC * BN * DI * DS;
  float* hb4     = arena;
  float* xdb     = (float*)alloc((size_t)MROWS * XDP * 4);
  short* xdbf    = (short*)alloc((size_t)MROWS * XDP * 2);
  short* dtb     = (short*)alloc((size_t)MROWS * DI * 2);
  float* xcur    = (float*)alloc((size_t)MROWS * DM * 4);

  // one-shot fused conversions (both layers)
  prep_k<<<(PR4 + 255) / 256, 256, 0, stream>>>(x, inw, outw, dtw, xpw,
      abuf, inw_bf, outw_bf, dtw_bf, xpw_bf);

  const float* lin = x;
  for (int l = 0; l < 2; ++l) {
    // in_proj: [2048,1024] x [4096,1024]^T -> bf16 xz
    gemm_mfma<1, 0><<<dim3((2 * DI) / 128, MROWS / 128), 256, 0, stream>>>(
        abuf, inw_bf + (size_t)l * 2 * DI * DM, nullptr, xzbf,
        MROWS, 2 * DI, DM, DM, DM, 2 * DI, nullptr, 0);

    conv_silu<<<(MROWS * DI) / 256, 256, 0, stream>>>(
        xzbf, convw + (size_t)l * DI * 4, convb + (size_t)l * DI, ubf);

    // x_proj: MFMA split-K=8 -> partials, then reduce
    gemm_mfma<0, 1><<<dim3(1, MROWS / 128, XPZ), 256, 0, stream>>>(
        ubf, xpw_bf + (size_t)l * XDP * DI, xpart, nullptr,
        MROWS, XDP, DI, DI, DI, XDP, nullptr, DI / XPZ);
    reduce_xp<<<(MROWS * XDP) / 256, 256, 0, stream>>>(xpart, xdb, xdbf);

    // dt_proj + softplus (MFMA, K=64) -> bf16 dt
    gemm_mfma<2, 0><<<dim3(DI / 128, MROWS / 128), 256, 0, stream>>>(
        xdbf, dtw_bf + (size_t)l * DI * RK, nullptr, dtb,
        MROWS, DI, RK, XDP, RK, DI, dtbi + (size_t)l * DI, 0);

    // chunked scan (channel-per-thread)
    scan_p1<<<NC * BN * (DI / 256), 256, 0, stream>>>(dtb, ubf, xdb,
        alog + (size_t)l * DI * DS, hloc, prodb);
    scan_p2<<<(BN * DI * DS) / 256, 256, 0, stream>>>(hloc, prodb, h0);
    scan_p3<<<NC * BN * (DI / 256), 256, 0, stream>>>(dtb, ubf, xdb, xzbf,
        alog + (size_t)l * DI * DS, dsk + (size_t)l * DI, h0, abuf);

    // out_proj: split-K=4 -> 4 fp32 partials (reduced inside ln_res)
    gemm_mfma<0, 1><<<dim3(DM / 128, MROWS / 128, OPZ), 256, 0, stream>>>(
        abuf, outw_bf + (size_t)l * DM * DI, hb4, nullptr,
        MROWS, DM, DI, DI, DI, DM, nullptr, DI / OPZ);

    float* lo = (l == 0) ? xcur : outp;
    short* lob = (l == 0) ? abuf : nullptr;
    ln_res<<<MROWS, 256, 0, stream>>>(hb4, lin,
        lnw + (size_t)l * DM, lnb + (size_t)l * DM, lo, lob);
    lin = xcur;
  }
}